// Round 1
// baseline (1037.608 us; speedup 1.0000x reference)
//
#include <hip/hip_runtime.h>
#include <stdint.h>

#define M_TRAIN 100000
#define D_DIM   768
#define C_DIM   128
#define NCLUST  500
#define CSIZE   100
#define NCLS    10
#define KSEL    10
#define NCAND   32
#define FLT_INF 3.402823466e38f

typedef __attribute__((ext_vector_type(8))) short bhalf8;
typedef __attribute__((ext_vector_type(4))) float f32x4;

// ws layout (bytes)
#define WS_KEYT   0LL         // 128*100000*4 = 51,200,000
#define WS_BIMG   51200000LL  // 768*128*2 = 196,608 (12 chunks x 16KB, pre-swizzled)
#define WS_CONT   51396608LL  // conceptT 128*768*4 = 393,216
#define WS_GRAM   51789824LL  // 128*128*4 = 65,536
#define WS_SCORE  51855360LL  // 500*128*4 = 256,000
#define WS_CT     52111360LL  // 768*10*4 = 30,720
#define WS_CAND   52142080LL  // 128*32*4 = 16,384
#define WS_PSUM   52158464LL  // 128*4

static __device__ __forceinline__ unsigned short f2bf(float f) {
    union { float f; unsigned int u; } x; x.f = f;
    unsigned int u = x.u;
    return (unsigned short)((u + 0x7fffu + ((u >> 16) & 1u)) >> 16);
}

// ---------------- prep: conceptT (f32 transpose) + pre-swizzled bf16 B image ----------------
__global__ void k_prep(const float* __restrict__ cpt, float* __restrict__ conceptT,
                       unsigned short* __restrict__ bimg) {
    int tid = blockIdx.x * 256 + threadIdx.x;  // 0..98303
    int d = tid >> 7, c = tid & 127;
    float v = cpt[tid];
    conceptT[c * D_DIM + d] = v;
    int kc = d >> 6, kin = d & 63;
    int ofs = kc * 16384 + (((c << 7) + (kin << 1)) ^ ((c & 7) << 4));
    *(unsigned short*)((char*)bimg + ofs) = f2bf(v);
}

// ---------------- gram = conceptT @ concept (128x128) ----------------
__global__ void k_gram(const float* __restrict__ cpt, float* __restrict__ gram) {
    int c1 = blockIdx.x, c2 = threadIdx.x;
    float s = 0.f;
    #pragma unroll 4
    for (int d = 0; d < D_DIM; ++d)
        s += cpt[d * 128 + c1] * cpt[d * 128 + c2];
    gram[c1 * 128 + c2] = s;
}

// ---------------- single-block: L2new + Gauss-Jordan solve gram*t = (W@C)^T, ct = C@t ----------------
__global__ void __launch_bounds__(512) k_solve(const float* __restrict__ gram,
        const float* __restrict__ whx, const float* __restrict__ cpt,
        const float* __restrict__ conceptT, float* __restrict__ ct,
        float* __restrict__ out_l2new) {
    __shared__ float aug[128][144];   // cols 0..127 gram, 128..137 rhs
    __shared__ float fvec[128];
    __shared__ float red[512];
    int t = threadIdx.x;
    float part = 0.f;
    for (int i = t; i < 128 * 128; i += 512) {
        int r = i >> 7, c = i & 127;
        float g = gram[i];
        aug[r][c] = g;
        if (r != c) part += g;
    }
    // rhs[c][j] = sum_d conceptT[c][d] * whx[j][d]
    for (int o = t; o < 128 * NCLS; o += 512) {
        int c = o / NCLS, j = o % NCLS;
        const float* cr = conceptT + c * D_DIM;
        const float* wr = whx + j * D_DIM;
        float s = 0.f;
        for (int d = 0; d < D_DIM; d += 4)
            s += cr[d]*wr[d] + cr[d+1]*wr[d+1] + cr[d+2]*wr[d+2] + cr[d+3]*wr[d+3];
        aug[c][128 + j] = s;
    }
    red[t] = part;
    __syncthreads();
    for (int s = 256; s > 0; s >>= 1) { if (t < s) red[t] += red[t + s]; __syncthreads(); }
    if (t == 0) out_l2new[0] = red[0] / 16384.0f;
    // Gauss-Jordan (SPD, no pivoting). cols < p are frozen zeros -> only touch (p,138)
    for (int p = 0; p < 128; ++p) {
        float inv = 1.0f / aug[p][p];
        int cnt = 137 - p;  // cols p+1..137
        for (int c = t; c < cnt; c += 512) aug[p][p + 1 + c] *= inv;
        if (t < 128 && t != p) fvec[t] = aug[t][p];
        __syncthreads();
        int total = 127 * cnt;
        for (int e = t; e < total; e += 512) {
            int r = e / cnt; r += (r >= p);
            int c = p + 1 + (e % cnt);
            aug[r][c] -= fvec[r] * aug[p][c];
        }
        __syncthreads();
    }
    // ct[d][j] = sum_c cpt[d][c] * t[c][j]
    for (int o = t; o < D_DIM * NCLS; o += 512) {
        int d = o / NCLS, j = o % NCLS;
        const float* crow = cpt + d * 128;
        float s = 0.f;
        #pragma unroll 4
        for (int c = 0; c < 128; ++c) s += crow[c] * aug[c][128 + j];
        ct[o] = s;
    }
}

// ---------------- y_pred = X @ ct + b (4096x10) ----------------
__global__ void k_ypred(const float* __restrict__ te, const float* __restrict__ ct,
                        const float* __restrict__ bhx, float* __restrict__ out) {
    __shared__ float ctT[NCLS][D_DIM];
    int t = threadIdx.x;
    for (int o = t; o < D_DIM * NCLS; o += 256) {
        int j = o / D_DIM, d = o % D_DIM;
        ctT[j][d] = ct[d * NCLS + j];
    }
    __syncthreads();
    int r = t >> 5, l = t & 31;
    long row = (long)blockIdx.x * 8 + r;
    const float* er = te + row * D_DIM;
    float acc[NCLS];
    #pragma unroll
    for (int j = 0; j < NCLS; ++j) acc[j] = 0.f;
    for (int d0 = l * 4; d0 < D_DIM; d0 += 128) {
        float4 e = *(const float4*)(er + d0);
        #pragma unroll
        for (int j = 0; j < NCLS; ++j) {
            float4 cc = *(const float4*)(&ctT[j][d0]);
            acc[j] += e.x*cc.x + e.y*cc.y + e.z*cc.z + e.w*cc.w;
        }
    }
    #pragma unroll
    for (int j = 0; j < NCLS; ++j) {
        #pragma unroll
        for (int m = 16; m > 0; m >>= 1) acc[j] += __shfl_xor(acc[j], m);
    }
    if (l == 0) {
        #pragma unroll
        for (int j = 0; j < NCLS; ++j) out[row * NCLS + j] = acc[j] + bhx[j];
    }
}

// ---------------- fused cluster mean + |mean @ concept_normalized| ----------------
__global__ void k_score(const float* __restrict__ clus, const float* __restrict__ cpt,
                        const float* __restrict__ gram, float* __restrict__ scoreM) {
    __shared__ float mean_s[D_DIM];
    int cl = blockIdx.x, t = threadIdx.x;
    if (t < 192) {
        float ax = 0.f, ay = 0.f, az = 0.f, aw = 0.f;
        const float* base = clus + (long)cl * CSIZE * D_DIM + t * 4;
        for (int s = 0; s < CSIZE; s += 4) {
            float4 v0 = *(const float4*)(base + (long)s * D_DIM);
            float4 v1 = *(const float4*)(base + (long)(s + 1) * D_DIM);
            float4 v2 = *(const float4*)(base + (long)(s + 2) * D_DIM);
            float4 v3 = *(const float4*)(base + (long)(s + 3) * D_DIM);
            ax += v0.x + v1.x + v2.x + v3.x;
            ay += v0.y + v1.y + v2.y + v3.y;
            az += v0.z + v1.z + v2.z + v3.z;
            aw += v0.w + v1.w + v2.w + v3.w;
        }
        const float k = 1.0f / CSIZE;
        mean_s[t * 4 + 0] = ax * k; mean_s[t * 4 + 1] = ay * k;
        mean_s[t * 4 + 2] = az * k; mean_s[t * 4 + 3] = aw * k;
    }
    __syncthreads();
    if (t < 128) {
        float s = 0.f;
        #pragma unroll 4
        for (int d = 0; d < D_DIM; ++d) s += mean_s[d] * cpt[d * 128 + t];
        float cn = fmaxf(sqrtf(gram[t * 129]), 1e-12f);
        scoreM[cl * 128 + t] = fabsf(s) / cn;
    }
}

// ---------------- L1old, L2old from scoreM ----------------
__global__ void __launch_bounds__(1024) k_old(const float* __restrict__ scoreM,
                                              float* __restrict__ out01) {
    __shared__ float snorm_s[128];
    __shared__ float red1[1024];
    __shared__ float wred[16];
    __shared__ float trace_tot;
    int t = threadIdx.x;
    float l1p = 0.f, trp = 0.f;
    if (t < 128) {
        float ss = 0.f, sm = 0.f;
        for (int cl = 0; cl < NCLUST; ++cl) {
            float v = scoreM[cl * 128 + t];
            ss += v * v; sm += v;
        }
        float nn = fmaxf(sqrtf(ss), 1e-12f);
        snorm_s[t] = nn;
        l1p = sm / nn;
        trp = ss / (nn * nn);
    }
    red1[t] = l1p;
    __syncthreads();
    for (int s = 512; s > 0; s >>= 1) { if (t < s) red1[t] += red1[t + s]; __syncthreads(); }
    if (t == 0) out01[0] = red1[0];
    __syncthreads();
    red1[t] = trp;
    __syncthreads();
    for (int s = 512; s > 0; s >>= 1) { if (t < s) red1[t] += red1[t + s]; __syncthreads(); }
    if (t == 0) trace_tot = red1[0];
    __syncthreads();
    int w = t >> 6, lane = t & 63;
    float rsq = 0.f;
    for (int cl = w; cl < NCLUST; cl += 16) {
        float v = scoreM[cl * 128 + lane] / snorm_s[lane]
                + scoreM[cl * 128 + 64 + lane] / snorm_s[64 + lane];
        #pragma unroll
        for (int m = 32; m > 0; m >>= 1) v += __shfl_xor(v, m);
        if (lane == 0) rsq += v * v;
    }
    if (lane == 0) wred[w] = rsq;
    __syncthreads();
    if (t == 0) {
        float s = 0.f;
        for (int i = 0; i < 16; ++i) s += wred[i];
        out01[1] = s - trace_tot;
    }
}

// ---------------- big MFMA: keyT[c][n] = e_sq[n] - 2*(E@C)[n][c] ----------------
__global__ void __launch_bounds__(256) k_P(const float* __restrict__ E,
        const unsigned short* __restrict__ bimg, float* __restrict__ keyT) {
    __shared__ unsigned short Alds[128 * 64];  // [row][k] bf16, XOR-swizzled
    __shared__ unsigned short Blds[128 * 64];  // [c][k]  bf16, XOR-swizzled (prebaked)
    __shared__ float esq_s[128];
    int t = threadIdx.x;
    int rowbase = blockIdx.x * 128;
    int lane = t & 63, w = t >> 6;
    int wr = w >> 1, wc = w & 1;
    const f32x4 vzero = {0.f, 0.f, 0.f, 0.f};
    f32x4 acc[4][4];
    #pragma unroll
    for (int m = 0; m < 4; ++m)
        #pragma unroll
        for (int n = 0; n < 4; ++n) acc[m][n] = vzero;
    float esq_p[4] = {0.f, 0.f, 0.f, 0.f};
    char* Ab = (char*)Alds;
    char* Bb = (char*)Blds;
    int g = t >> 3, k8 = t & 7;

    for (int ks = 0; ks < 12; ++ks) {
        // stage A (f32 -> bf16, fused e_sq)
        #pragma unroll
        for (int p = 0; p < 4; ++p) {
            int row = 32 * p + g;
            int grow = rowbase + row;
            float4 v0 = {0.f,0.f,0.f,0.f}, v1 = {0.f,0.f,0.f,0.f};
            if (grow < M_TRAIN) {
                const float* src = E + (long)grow * D_DIM + ks * 64 + k8 * 8;
                v0 = *(const float4*)(src);
                v1 = *(const float4*)(src + 4);
            }
            esq_p[p] += v0.x*v0.x + v0.y*v0.y + v0.z*v0.z + v0.w*v0.w
                      + v1.x*v1.x + v1.y*v1.y + v1.z*v1.z + v1.w*v1.w;
            bhalf8 h;
            h[0] = (short)f2bf(v0.x); h[1] = (short)f2bf(v0.y);
            h[2] = (short)f2bf(v0.z); h[3] = (short)f2bf(v0.w);
            h[4] = (short)f2bf(v1.x); h[5] = (short)f2bf(v1.y);
            h[6] = (short)f2bf(v1.z); h[7] = (short)f2bf(v1.w);
            int byte = (row * 128 + k8 * 16) ^ ((row & 7) << 4);
            *(bhalf8*)(Ab + byte) = h;
        }
        // stage B: linear 16KB copy (pre-swizzled in global)
        {
            const char* src = (const char*)bimg + ks * 16384;
            #pragma unroll
            for (int i = 0; i < 4; ++i) {
                int idx = i * 256 + t;
                *(bhalf8*)(Bb + idx * 16) = *(const bhalf8*)(src + idx * 16);
            }
        }
        __syncthreads();
        bhalf8 af[4][2], bf[4][2];
        int kb = (lane >> 4) * 16;
        #pragma unroll
        for (int m = 0; m < 4; ++m) {
            int row = wr * 64 + m * 16 + (lane & 15);
            int b0 = row * 128, sw = (row & 7) << 4;
            af[m][0] = *(const bhalf8*)(Ab + ((b0 + kb) ^ sw));
            af[m][1] = *(const bhalf8*)(Ab + ((b0 + kb + 64) ^ sw));
        }
        #pragma unroll
        for (int n = 0; n < 4; ++n) {
            int c = wc * 64 + n * 16 + (lane & 15);
            int b0 = c * 128, sw = (c & 7) << 4;
            bf[n][0] = *(const bhalf8*)(Bb + ((b0 + kb) ^ sw));
            bf[n][1] = *(const bhalf8*)(Bb + ((b0 + kb + 64) ^ sw));
        }
        #pragma unroll
        for (int m = 0; m < 4; ++m)
            #pragma unroll
            for (int n = 0; n < 4; ++n) {
                acc[m][n] = __builtin_amdgcn_mfma_f32_16x16x32_bf16(af[m][0], bf[n][0], acc[m][n], 0, 0, 0);
                acc[m][n] = __builtin_amdgcn_mfma_f32_16x16x32_bf16(af[m][1], bf[n][1], acc[m][n], 0, 0, 0);
            }
        __syncthreads();
    }
    #pragma unroll
    for (int p = 0; p < 4; ++p) {
        float v = esq_p[p];
        v += __shfl_xor(v, 1); v += __shfl_xor(v, 2); v += __shfl_xor(v, 4);
        if (k8 == 0) esq_s[32 * p + g] = v;
    }
    __syncthreads();
    #pragma unroll
    for (int m = 0; m < 4; ++m) {
        int r0 = wr * 64 + m * 16 + (lane >> 4) * 4;
        if (rowbase + r0 >= M_TRAIN) continue;
        float e0 = esq_s[r0], e1 = esq_s[r0 + 1], e2 = esq_s[r0 + 2], e3 = esq_s[r0 + 3];
        #pragma unroll
        for (int n = 0; n < 4; ++n) {
            int c = wc * 64 + n * 16 + (lane & 15);
            float4 kv;
            kv.x = e0 - 2.f * acc[m][n][0];
            kv.y = e1 - 2.f * acc[m][n][1];
            kv.z = e2 - 2.f * acc[m][n][2];
            kv.w = e3 - 2.f * acc[m][n][3];
            *(float4*)(keyT + (long)c * M_TRAIN + rowbase + r0) = kv;
        }
    }
}

// ---------------- per-concept approximate top-32 ----------------
__global__ void __launch_bounds__(256) k_select(const float* __restrict__ keyT,
                                                int* __restrict__ cand) {
    __shared__ float sk[2048];
    __shared__ int si[2048];
    __shared__ float wk[4]; __shared__ int wi[4], wsl[4];
    int c = blockIdx.x, t = threadIdx.x;
    const float* col = keyT + (long)c * M_TRAIN;
    float tk[8]; int ti[8];
    #pragma unroll
    for (int i = 0; i < 8; ++i) { tk[i] = FLT_INF; ti[i] = 0x7fffffff; }
    for (int i = t; i < M_TRAIN / 4; i += 256) {
        float4 v = *(const float4*)(col + i * 4);
        int idx = i * 4;
        float vv[4] = {v.x, v.y, v.z, v.w};
        #pragma unroll
        for (int q = 0; q < 4; ++q) {
            float cv = vv[q]; int ci = idx + q;
            if (cv < tk[7] || (cv == tk[7] && ci < ti[7])) {
                #pragma unroll
                for (int j = 0; j < 8; ++j) {
                    bool sw = (cv < tk[j]) || (cv == tk[j] && ci < ti[j]);
                    float ok = tk[j]; int oi = ti[j];
                    if (sw) { tk[j] = cv; ti[j] = ci; cv = ok; ci = oi; }
                }
            }
        }
    }
    #pragma unroll
    for (int i = 0; i < 8; ++i) { sk[t * 8 + i] = tk[i]; si[t * 8 + i] = ti[i]; }
    __syncthreads();
    int lane = t & 63, w = t >> 6;
    for (int sel = 0; sel < NCAND; ++sel) {
        float bk = FLT_INF; int bi = 0x7fffffff, bs = -1;
        #pragma unroll
        for (int i = 0; i < 8; ++i) {
            int s = t * 8 + i;
            float v = sk[s];
            if (v < bk || (v == bk && si[s] < bi)) { bk = v; bi = si[s]; bs = s; }
        }
        #pragma unroll
        for (int m = 32; m > 0; m >>= 1) {
            float ok = __shfl_xor(bk, m); int oi = __shfl_xor(bi, m); int os = __shfl_xor(bs, m);
            if (ok < bk || (ok == bk && oi < bi)) { bk = ok; bi = oi; bs = os; }
        }
        if (lane == 0) { wk[w] = bk; wi[w] = bi; wsl[w] = bs; }
        __syncthreads();
        if (t == 0) {
            float fk = wk[0]; int fi = wi[0], fs = wsl[0];
            for (int i = 1; i < 4; ++i)
                if (wk[i] < fk || (wk[i] == fk && wi[i] < fi)) { fk = wk[i]; fi = wi[i]; fs = wsl[i]; }
            cand[c * NCAND + sel] = fi;
            sk[fs] = FLT_INF; si[fs] = 0x7fffffff;
        }
        __syncthreads();
    }
}

// ---------------- exact f32 re-rank of 32 candidates, sum top-10 dots ----------------
__global__ void k_refine(const float* __restrict__ E, const float* __restrict__ conceptT,
                         const int* __restrict__ cand, float* __restrict__ psum) {
    __shared__ float skey[NCAND], sdot[NCAND];
    __shared__ int sidx[NCAND];
    int c = blockIdx.x, t = threadIdx.x;
    int g = t >> 3, l8 = t & 7;
    int idx = cand[c * NCAND + g];
    const float* er = E + (long)idx * D_DIM;
    const float* cr = conceptT + c * D_DIM;
    float dot = 0.f, ss = 0.f;
    for (int d0 = l8 * 4; d0 < D_DIM; d0 += 32) {
        float4 e = *(const float4*)(er + d0);
        float4 cc = *(const float4*)(cr + d0);
        dot += e.x*cc.x + e.y*cc.y + e.z*cc.z + e.w*cc.w;
        ss  += e.x*e.x + e.y*e.y + e.z*e.z + e.w*e.w;
    }
    dot += __shfl_xor(dot, 1); dot += __shfl_xor(dot, 2); dot += __shfl_xor(dot, 4);
    ss  += __shfl_xor(ss, 1);  ss  += __shfl_xor(ss, 2);  ss  += __shfl_xor(ss, 4);
    if (l8 == 0) { skey[g] = ss - 2.f * dot; sdot[g] = dot; sidx[g] = idx; }
    __syncthreads();
    if (t == 0) {
        float sum = 0.f;
        unsigned used = 0u;
        for (int s = 0; s < KSEL; ++s) {
            float bk = FLT_INF; int bi = 0x7fffffff, bs = 0;
            for (int i = 0; i < NCAND; ++i) {
                if ((used >> i) & 1u) continue;
                if (skey[i] < bk || (skey[i] == bk && sidx[i] < bi)) { bk = skey[i]; bi = sidx[i]; bs = i; }
            }
            used |= (1u << bs);
            sum += sdot[bs];
        }
        psum[c] = sum;
    }
}

__global__ void k_finalize(const float* __restrict__ psum, float* __restrict__ out2) {
    __shared__ float red[128];
    int t = threadIdx.x;
    red[t] = psum[t];
    __syncthreads();
    for (int s = 64; s > 0; s >>= 1) { if (t < s) red[t] += red[t + s]; __syncthreads(); }
    if (t == 0) out2[0] = red[0] * (1.0f / (C_DIM * KSEL));
}

extern "C" void kernel_launch(void* const* d_in, const int* in_sizes, int n_in,
                              void* d_out, int out_size, void* d_ws, size_t ws_size,
                              hipStream_t stream) {
    (void)in_sizes; (void)n_in; (void)out_size; (void)ws_size;
    const float* te   = (const float*)d_in[0];  // 4096x768
    const float* cpt  = (const float*)d_in[1];  // 768x128
    const float* clus = (const float*)d_in[2];  // 500x100x768
    const float* tes  = (const float*)d_in[3];  // 100000x768
    const float* whx  = (const float*)d_in[4];  // 10x768
    const float* bhx  = (const float*)d_in[5];  // 10
    float* out = (float*)d_out;                 // 40960 y_pred + 4 scalars
    char* ws = (char*)d_ws;
    float* keyT           = (float*)(ws + WS_KEYT);
    unsigned short* bimg  = (unsigned short*)(ws + WS_BIMG);
    float* conceptT       = (float*)(ws + WS_CONT);
    float* gram           = (float*)(ws + WS_GRAM);
    float* scoreM         = (float*)(ws + WS_SCORE);
    float* ct             = (float*)(ws + WS_CT);
    int* cand             = (int*)(ws + WS_CAND);
    float* psum           = (float*)(ws + WS_PSUM);

    k_prep    <<<dim3(384), dim3(256), 0, stream>>>(cpt, conceptT, bimg);
    k_gram    <<<dim3(128), dim3(128), 0, stream>>>(cpt, gram);
    k_solve   <<<dim3(1),   dim3(512), 0, stream>>>(gram, whx, cpt, conceptT, ct, out + 40963);
    k_ypred   <<<dim3(512), dim3(256), 0, stream>>>(te, ct, bhx, out);
    k_score   <<<dim3(500), dim3(256), 0, stream>>>(clus, cpt, gram, scoreM);
    k_old     <<<dim3(1),   dim3(1024),0, stream>>>(scoreM, out + 40960);
    k_P       <<<dim3((M_TRAIN + 127) / 128), dim3(256), 0, stream>>>(tes, bimg, keyT);
    k_select  <<<dim3(128), dim3(256), 0, stream>>>(keyT, cand);
    k_refine  <<<dim3(128), dim3(256), 0, stream>>>(tes, conceptT, cand, psum);
    k_finalize<<<dim3(1),   dim3(128), 0, stream>>>(psum, out + 40962);
}

// Round 2
// 882.676 us; speedup vs baseline: 1.1755x; 1.1755x over previous
//
#include <hip/hip_runtime.h>
#include <stdint.h>

#define M_TRAIN 100000
#define D_DIM   768
#define C_DIM   128
#define NCLUST  500
#define CSIZE   100
#define NCLS    10
#define KSEL    10
#define NCAND   32
#define FLT_INF 3.402823466e38f

typedef __attribute__((ext_vector_type(8))) short bhalf8;
typedef __attribute__((ext_vector_type(4))) float f32x4;

// ws layout (bytes)
#define WS_KEYT   0LL         // 128*100000*4 = 51,200,000
#define WS_BIMG   51200000LL  // 768*128*2 = 196,608 (12 chunks x 16KB, pre-swizzled)
#define WS_CONT   51396608LL  // conceptT 128*768*4 = 393,216
#define WS_GRAM   51789824LL  // 128*128*4 = 65,536
#define WS_SCORE  51855360LL  // 500*128*4 = 256,000
#define WS_CT     52111360LL  // 768*10*4 = 30,720
#define WS_CAND   52142080LL  // 128*32*4 = 16,384
#define WS_PSUM   52158464LL  // 128*4

static __device__ __forceinline__ unsigned short f2bf(float f) {
    union { float f; unsigned int u; } x; x.f = f;
    unsigned int u = x.u;
    return (unsigned short)((u + 0x7fffu + ((u >> 16) & 1u)) >> 16);
}

// ---------------- prep: conceptT (f32 transpose) + pre-swizzled bf16 B image ----------------
__global__ void k_prep(const float* __restrict__ cpt, float* __restrict__ conceptT,
                       unsigned short* __restrict__ bimg) {
    int tid = blockIdx.x * 256 + threadIdx.x;  // 0..98303
    int d = tid >> 7, c = tid & 127;
    float v = cpt[tid];
    conceptT[c * D_DIM + d] = v;
    int kc = d >> 6, kin = d & 63;
    int ofs = kc * 16384 + (((c << 7) + (kin << 1)) ^ ((c & 7) << 4));
    *(unsigned short*)((char*)bimg + ofs) = f2bf(v);
}

// ---------------- gram = conceptT @ concept (128x128) ----------------
__global__ void k_gram(const float* __restrict__ cpt, float* __restrict__ gram) {
    int c1 = blockIdx.x, c2 = threadIdx.x;
    float s = 0.f;
    #pragma unroll 4
    for (int d = 0; d < D_DIM; ++d)
        s += cpt[d * 128 + c1] * cpt[d * 128 + c2];
    gram[c1 * 128 + c2] = s;
}

// ---------------- single-block: L2new + unnormalized Gauss-Jordan, ct = C@t ----------------
// Thread t owns row r = t&127, col-group j = t>>7 (stride-4 cols). One barrier
// per pivot: updates write rows!=p, cols>p only; reads touch row p and col p
// only -> disjoint. Diagonal divide deferred to the end.
#define STR 139   // odd LDS row stride: consecutive r -> all 32 banks, conflict-free
__global__ void __launch_bounds__(512) k_solve(const float* __restrict__ gram,
        const float* __restrict__ whx, const float* __restrict__ cpt,
        const float* __restrict__ conceptT, float* __restrict__ ct,
        float* __restrict__ out_l2new) {
    __shared__ float aug[128 * STR];    // cols 0..127 gram, 128..137 rhs
    __shared__ float tsol[128 * NCLS];
    __shared__ float red[512];
    int t = threadIdx.x;
    int r = t & 127, j = t >> 7;
    float part = 0.f;
    for (int i = t; i < 128 * 128; i += 512) {
        int rr = i >> 7, cc = i & 127;
        float g = gram[i];
        aug[rr * STR + cc] = g;
        if (rr != cc) part += g;
    }
    // rhs[c][jj] = sum_d conceptT[c][d] * whx[jj][d]
    for (int o = t; o < 128 * NCLS; o += 512) {
        int cc = o / NCLS, jj = o - cc * NCLS;
        const float* cr = conceptT + cc * D_DIM;
        const float* wr = whx + jj * D_DIM;
        float s = 0.f;
        for (int d = 0; d < D_DIM; d += 4)
            s += cr[d]*wr[d] + cr[d+1]*wr[d+1] + cr[d+2]*wr[d+2] + cr[d+3]*wr[d+3];
        aug[cc * STR + 128 + jj] = s;
    }
    red[t] = part;
    __syncthreads();
    for (int s = 256; s > 0; s >>= 1) { if (t < s) red[t] += red[t + s]; __syncthreads(); }
    if (t == 0) out_l2new[0] = red[0] / 16384.0f;

    // Gauss-Jordan without row normalization, 1 barrier per pivot, no div/mod.
    for (int p = 0; p < 128; ++p) {
        __syncthreads();
        float inv = 1.0f / aug[p * STR + p];      // broadcast read
        float f = aug[r * STR + p] * inv;         // col-p read (not written this pivot)
        if (r != p) {
            for (int cidx = p + 1 + j; cidx < 138; cidx += 4)
                aug[r * STR + cidx] -= f * aug[p * STR + cidx];  // row-p read = broadcast
        }
    }
    __syncthreads();
    // t_sol = rhs / diag
    for (int o = t; o < 128 * NCLS; o += 512) {
        int cc = o / NCLS, jj = o - cc * NCLS;
        tsol[o] = aug[cc * STR + 128 + jj] / aug[cc * STR + cc];
    }
    __syncthreads();
    // ct[d][jj] = sum_c cpt[d][c] * t_sol[c][jj]
    for (int o = t; o < D_DIM * NCLS; o += 512) {
        int d = o / NCLS, jj = o - d * NCLS;
        const float* crow = cpt + d * 128;
        float s = 0.f;
        #pragma unroll 4
        for (int cc = 0; cc < 128; ++cc) s += crow[cc] * tsol[cc * NCLS + jj];
        ct[o] = s;
    }
}

// ---------------- y_pred = X @ ct + b (4096x10) ----------------
__global__ void k_ypred(const float* __restrict__ te, const float* __restrict__ ct,
                        const float* __restrict__ bhx, float* __restrict__ out) {
    __shared__ float ctT[NCLS][D_DIM];
    int t = threadIdx.x;
    for (int o = t; o < D_DIM * NCLS; o += 256) {
        int j = o / D_DIM, d = o % D_DIM;
        ctT[j][d] = ct[d * NCLS + j];
    }
    __syncthreads();
    int r = t >> 5, l = t & 31;
    long row = (long)blockIdx.x * 8 + r;
    const float* er = te + row * D_DIM;
    float acc[NCLS];
    #pragma unroll
    for (int j = 0; j < NCLS; ++j) acc[j] = 0.f;
    for (int d0 = l * 4; d0 < D_DIM; d0 += 128) {
        float4 e = *(const float4*)(er + d0);
        #pragma unroll
        for (int j = 0; j < NCLS; ++j) {
            float4 cc = *(const float4*)(&ctT[j][d0]);
            acc[j] += e.x*cc.x + e.y*cc.y + e.z*cc.z + e.w*cc.w;
        }
    }
    #pragma unroll
    for (int j = 0; j < NCLS; ++j) {
        #pragma unroll
        for (int m = 16; m > 0; m >>= 1) acc[j] += __shfl_xor(acc[j], m);
    }
    if (l == 0) {
        #pragma unroll
        for (int j = 0; j < NCLS; ++j) out[row * NCLS + j] = acc[j] + bhx[j];
    }
}

// ---------------- fused cluster mean + |mean @ concept_normalized| ----------------
__global__ void k_score(const float* __restrict__ clus, const float* __restrict__ cpt,
                        const float* __restrict__ gram, float* __restrict__ scoreM) {
    __shared__ float mean_s[D_DIM];
    int cl = blockIdx.x, t = threadIdx.x;
    if (t < 192) {
        float ax = 0.f, ay = 0.f, az = 0.f, aw = 0.f;
        const float* base = clus + (long)cl * CSIZE * D_DIM + t * 4;
        for (int s = 0; s < CSIZE; s += 4) {
            float4 v0 = *(const float4*)(base + (long)s * D_DIM);
            float4 v1 = *(const float4*)(base + (long)(s + 1) * D_DIM);
            float4 v2 = *(const float4*)(base + (long)(s + 2) * D_DIM);
            float4 v3 = *(const float4*)(base + (long)(s + 3) * D_DIM);
            ax += v0.x + v1.x + v2.x + v3.x;
            ay += v0.y + v1.y + v2.y + v3.y;
            az += v0.z + v1.z + v2.z + v3.z;
            aw += v0.w + v1.w + v2.w + v3.w;
        }
        const float k = 1.0f / CSIZE;
        mean_s[t * 4 + 0] = ax * k; mean_s[t * 4 + 1] = ay * k;
        mean_s[t * 4 + 2] = az * k; mean_s[t * 4 + 3] = aw * k;
    }
    __syncthreads();
    if (t < 128) {
        float s = 0.f;
        #pragma unroll 4
        for (int d = 0; d < D_DIM; ++d) s += mean_s[d] * cpt[d * 128 + t];
        float cn = fmaxf(sqrtf(gram[t * 129]), 1e-12f);
        scoreM[cl * 128 + t] = fabsf(s) / cn;
    }
}

// ---------------- L1old, L2old from scoreM (all 1024 threads active) ----------------
__global__ void __launch_bounds__(1024) k_old(const float* __restrict__ scoreM,
                                              float* __restrict__ out01) {
    __shared__ float ss8[8][128];
    __shared__ float sm8[8][128];
    __shared__ float sinv[128];
    __shared__ float redA[128];
    __shared__ float redB[128];
    __shared__ float wred[16];
    __shared__ float trace_tot_s;
    int t = threadIdx.x;
    int c = t & 127, w8 = t >> 7;
    float ss = 0.f, sm = 0.f;
    for (int cl = w8; cl < NCLUST; cl += 8) {
        float v = scoreM[cl * 128 + c];
        ss += v * v; sm += v;
    }
    ss8[w8][c] = ss; sm8[w8][c] = sm;
    __syncthreads();
    if (t < 128) {
        float S = 0.f, M = 0.f;
        #pragma unroll
        for (int i = 0; i < 8; ++i) { S += ss8[i][t]; M += sm8[i][t]; }
        float nn = fmaxf(sqrtf(S), 1e-12f);
        float iv = 1.0f / nn;
        sinv[t] = iv;
        redA[t] = M * iv;
        redB[t] = S * iv * iv;
    }
    __syncthreads();
    if (t < 64) {
        float a = redA[t] + redA[t + 64];
        float b = redB[t] + redB[t + 64];
        #pragma unroll
        for (int m = 32; m > 0; m >>= 1) { a += __shfl_xor(a, m); b += __shfl_xor(b, m); }
        if (t == 0) { out01[0] = a; trace_tot_s = b; }
    }
    __syncthreads();
    int w = t >> 6, lane = t & 63;
    float rsq = 0.f;
    for (int cl = w; cl < NCLUST; cl += 16) {
        float v = scoreM[cl * 128 + lane] * sinv[lane]
                + scoreM[cl * 128 + 64 + lane] * sinv[64 + lane];
        #pragma unroll
        for (int m = 32; m > 0; m >>= 1) v += __shfl_xor(v, m);
        if (lane == 0) rsq += v * v;
    }
    if (lane == 0) wred[w] = rsq;
    __syncthreads();
    if (t == 0) {
        float s = 0.f;
        for (int i = 0; i < 16; ++i) s += wred[i];
        out01[1] = s - trace_tot_s;
    }
}

// ---------------- big MFMA: keyT[c][n] = e_sq[n] - 2*(E@C)[n][c] ----------------
__global__ void __launch_bounds__(256) k_P(const float* __restrict__ E,
        const unsigned short* __restrict__ bimg, float* __restrict__ keyT) {
    __shared__ unsigned short Alds[128 * 64];  // [row][k] bf16, XOR-swizzled
    __shared__ unsigned short Blds[128 * 64];  // [c][k]  bf16, XOR-swizzled (prebaked)
    __shared__ float esq_s[128];
    int t = threadIdx.x;
    int rowbase = blockIdx.x * 128;
    int lane = t & 63, w = t >> 6;
    int wr = w >> 1, wc = w & 1;
    const f32x4 vzero = {0.f, 0.f, 0.f, 0.f};
    f32x4 acc[4][4];
    #pragma unroll
    for (int m = 0; m < 4; ++m)
        #pragma unroll
        for (int n = 0; n < 4; ++n) acc[m][n] = vzero;
    float esq_p[4] = {0.f, 0.f, 0.f, 0.f};
    char* Ab = (char*)Alds;
    char* Bb = (char*)Blds;
    int g = t >> 3, k8 = t & 7;

    for (int ks = 0; ks < 12; ++ks) {
        // stage A (f32 -> bf16, fused e_sq)
        #pragma unroll
        for (int p = 0; p < 4; ++p) {
            int row = 32 * p + g;
            int grow = rowbase + row;
            float4 v0 = {0.f,0.f,0.f,0.f}, v1 = {0.f,0.f,0.f,0.f};
            if (grow < M_TRAIN) {
                const float* src = E + (long)grow * D_DIM + ks * 64 + k8 * 8;
                v0 = *(const float4*)(src);
                v1 = *(const float4*)(src + 4);
            }
            esq_p[p] += v0.x*v0.x + v0.y*v0.y + v0.z*v0.z + v0.w*v0.w
                      + v1.x*v1.x + v1.y*v1.y + v1.z*v1.z + v1.w*v1.w;
            bhalf8 h;
            h[0] = (short)f2bf(v0.x); h[1] = (short)f2bf(v0.y);
            h[2] = (short)f2bf(v0.z); h[3] = (short)f2bf(v0.w);
            h[4] = (short)f2bf(v1.x); h[5] = (short)f2bf(v1.y);
            h[6] = (short)f2bf(v1.z); h[7] = (short)f2bf(v1.w);
            int byte = (row * 128 + k8 * 16) ^ ((row & 7) << 4);
            *(bhalf8*)(Ab + byte) = h;
        }
        // stage B: linear 16KB copy (pre-swizzled in global)
        {
            const char* src = (const char*)bimg + ks * 16384;
            #pragma unroll
            for (int i = 0; i < 4; ++i) {
                int idx = i * 256 + t;
                *(bhalf8*)(Bb + idx * 16) = *(const bhalf8*)(src + idx * 16);
            }
        }
        __syncthreads();
        bhalf8 af[4][2], bf[4][2];
        int kb = (lane >> 4) * 16;
        #pragma unroll
        for (int m = 0; m < 4; ++m) {
            int row = wr * 64 + m * 16 + (lane & 15);
            int b0 = row * 128, sw = (row & 7) << 4;
            af[m][0] = *(const bhalf8*)(Ab + ((b0 + kb) ^ sw));
            af[m][1] = *(const bhalf8*)(Ab + ((b0 + kb + 64) ^ sw));
        }
        #pragma unroll
        for (int n = 0; n < 4; ++n) {
            int c = wc * 64 + n * 16 + (lane & 15);
            int b0 = c * 128, sw = (c & 7) << 4;
            bf[n][0] = *(const bhalf8*)(Bb + ((b0 + kb) ^ sw));
            bf[n][1] = *(const bhalf8*)(Bb + ((b0 + kb + 64) ^ sw));
        }
        #pragma unroll
        for (int m = 0; m < 4; ++m)
            #pragma unroll
            for (int n = 0; n < 4; ++n) {
                acc[m][n] = __builtin_amdgcn_mfma_f32_16x16x32_bf16(af[m][0], bf[n][0], acc[m][n], 0, 0, 0);
                acc[m][n] = __builtin_amdgcn_mfma_f32_16x16x32_bf16(af[m][1], bf[n][1], acc[m][n], 0, 0, 0);
            }
        __syncthreads();
    }
    #pragma unroll
    for (int p = 0; p < 4; ++p) {
        float v = esq_p[p];
        v += __shfl_xor(v, 1); v += __shfl_xor(v, 2); v += __shfl_xor(v, 4);
        if (k8 == 0) esq_s[32 * p + g] = v;
    }
    __syncthreads();
    #pragma unroll
    for (int m = 0; m < 4; ++m) {
        int r0 = wr * 64 + m * 16 + (lane >> 4) * 4;
        if (rowbase + r0 >= M_TRAIN) continue;
        float e0 = esq_s[r0], e1 = esq_s[r0 + 1], e2 = esq_s[r0 + 2], e3 = esq_s[r0 + 3];
        #pragma unroll
        for (int n = 0; n < 4; ++n) {
            int c = wc * 64 + n * 16 + (lane & 15);
            float4 kv;
            kv.x = e0 - 2.f * acc[m][n][0];
            kv.y = e1 - 2.f * acc[m][n][1];
            kv.z = e2 - 2.f * acc[m][n][2];
            kv.w = e3 - 2.f * acc[m][n][3];
            *(float4*)(keyT + (long)c * M_TRAIN + rowbase + r0) = kv;
        }
    }
}

// ---------------- per-concept approximate top-32 ----------------
__global__ void __launch_bounds__(256) k_select(const float* __restrict__ keyT,
                                                int* __restrict__ cand) {
    __shared__ float sk[2048];
    __shared__ int si[2048];
    __shared__ float wk[4]; __shared__ int wi[4], wsl[4];
    int c = blockIdx.x, t = threadIdx.x;
    const float* col = keyT + (long)c * M_TRAIN;
    float tk[8]; int ti[8];
    #pragma unroll
    for (int i = 0; i < 8; ++i) { tk[i] = FLT_INF; ti[i] = 0x7fffffff; }
    for (int i = t; i < M_TRAIN / 4; i += 256) {
        float4 v = *(const float4*)(col + i * 4);
        int idx = i * 4;
        float vv[4] = {v.x, v.y, v.z, v.w};
        #pragma unroll
        for (int q = 0; q < 4; ++q) {
            float cv = vv[q]; int ci = idx + q;
            if (cv < tk[7] || (cv == tk[7] && ci < ti[7])) {
                #pragma unroll
                for (int j = 0; j < 8; ++j) {
                    bool sw = (cv < tk[j]) || (cv == tk[j] && ci < ti[j]);
                    float ok = tk[j]; int oi = ti[j];
                    if (sw) { tk[j] = cv; ti[j] = ci; cv = ok; ci = oi; }
                }
            }
        }
    }
    #pragma unroll
    for (int i = 0; i < 8; ++i) { sk[t * 8 + i] = tk[i]; si[t * 8 + i] = ti[i]; }
    __syncthreads();
    int lane = t & 63, w = t >> 6;
    for (int sel = 0; sel < NCAND; ++sel) {
        float bk = FLT_INF; int bi = 0x7fffffff, bs = -1;
        #pragma unroll
        for (int i = 0; i < 8; ++i) {
            int s = t * 8 + i;
            float v = sk[s];
            if (v < bk || (v == bk && si[s] < bi)) { bk = v; bi = si[s]; bs = s; }
        }
        #pragma unroll
        for (int m = 32; m > 0; m >>= 1) {
            float ok = __shfl_xor(bk, m); int oi = __shfl_xor(bi, m); int os = __shfl_xor(bs, m);
            if (ok < bk || (ok == bk && oi < bi)) { bk = ok; bi = oi; bs = os; }
        }
        if (lane == 0) { wk[w] = bk; wi[w] = bi; wsl[w] = bs; }
        __syncthreads();
        if (t == 0) {
            float fk = wk[0]; int fi = wi[0], fs = wsl[0];
            for (int i = 1; i < 4; ++i)
                if (wk[i] < fk || (wk[i] == fk && wi[i] < fi)) { fk = wk[i]; fi = wi[i]; fs = wsl[i]; }
            cand[c * NCAND + sel] = fi;
            sk[fs] = FLT_INF; si[fs] = 0x7fffffff;
        }
        __syncthreads();
    }
}

// ---------------- exact f32 re-rank of 32 candidates, sum top-10 dots ----------------
__global__ void k_refine(const float* __restrict__ E, const float* __restrict__ conceptT,
                         const int* __restrict__ cand, float* __restrict__ psum) {
    __shared__ float skey[NCAND], sdot[NCAND];
    __shared__ int sidx[NCAND];
    int c = blockIdx.x, t = threadIdx.x;
    int g = t >> 3, l8 = t & 7;
    int idx = cand[c * NCAND + g];
    const float* er = E + (long)idx * D_DIM;
    const float* cr = conceptT + c * D_DIM;
    float dot = 0.f, ss = 0.f;
    for (int d0 = l8 * 4; d0 < D_DIM; d0 += 32) {
        float4 e = *(const float4*)(er + d0);
        float4 cc = *(const float4*)(cr + d0);
        dot += e.x*cc.x + e.y*cc.y + e.z*cc.z + e.w*cc.w;
        ss  += e.x*e.x + e.y*e.y + e.z*e.z + e.w*e.w;
    }
    dot += __shfl_xor(dot, 1); dot += __shfl_xor(dot, 2); dot += __shfl_xor(dot, 4);
    ss  += __shfl_xor(ss, 1);  ss  += __shfl_xor(ss, 2);  ss  += __shfl_xor(ss, 4);
    if (l8 == 0) { skey[g] = ss - 2.f * dot; sdot[g] = dot; sidx[g] = idx; }
    __syncthreads();
    if (t == 0) {
        float sum = 0.f;
        unsigned used = 0u;
        for (int s = 0; s < KSEL; ++s) {
            float bk = FLT_INF; int bi = 0x7fffffff, bs = 0;
            for (int i = 0; i < NCAND; ++i) {
                if ((used >> i) & 1u) continue;
                if (skey[i] < bk || (skey[i] == bk && sidx[i] < bi)) { bk = skey[i]; bi = sidx[i]; bs = i; }
            }
            used |= (1u << bs);
            sum += sdot[bs];
        }
        psum[c] = sum;
    }
}

__global__ void k_finalize(const float* __restrict__ psum, float* __restrict__ out2) {
    __shared__ float red[128];
    int t = threadIdx.x;
    red[t] = psum[t];
    __syncthreads();
    for (int s = 64; s > 0; s >>= 1) { if (t < s) red[t] += red[t + s]; __syncthreads(); }
    if (t == 0) out2[0] = red[0] * (1.0f / (C_DIM * KSEL));
}

extern "C" void kernel_launch(void* const* d_in, const int* in_sizes, int n_in,
                              void* d_out, int out_size, void* d_ws, size_t ws_size,
                              hipStream_t stream) {
    (void)in_sizes; (void)n_in; (void)out_size; (void)ws_size;
    const float* te   = (const float*)d_in[0];  // 4096x768
    const float* cpt  = (const float*)d_in[1];  // 768x128
    const float* clus = (const float*)d_in[2];  // 500x100x768
    const float* tes  = (const float*)d_in[3];  // 100000x768
    const float* whx  = (const float*)d_in[4];  // 10x768
    const float* bhx  = (const float*)d_in[5];  // 10
    float* out = (float*)d_out;                 // 40960 y_pred + 4 scalars
    char* ws = (char*)d_ws;
    float* keyT           = (float*)(ws + WS_KEYT);
    unsigned short* bimg  = (unsigned short*)(ws + WS_BIMG);
    float* conceptT       = (float*)(ws + WS_CONT);
    float* gram           = (float*)(ws + WS_GRAM);
    float* scoreM         = (float*)(ws + WS_SCORE);
    float* ct             = (float*)(ws + WS_CT);
    int* cand             = (int*)(ws + WS_CAND);
    float* psum           = (float*)(ws + WS_PSUM);

    k_prep    <<<dim3(384), dim3(256), 0, stream>>>(cpt, conceptT, bimg);
    k_gram    <<<dim3(128), dim3(128), 0, stream>>>(cpt, gram);
    k_solve   <<<dim3(1),   dim3(512), 0, stream>>>(gram, whx, cpt, conceptT, ct, out + 40963);
    k_ypred   <<<dim3(512), dim3(256), 0, stream>>>(te, ct, bhx, out);
    k_score   <<<dim3(500), dim3(256), 0, stream>>>(clus, cpt, gram, scoreM);
    k_old     <<<dim3(1),   dim3(1024),0, stream>>>(scoreM, out + 40960);
    k_P       <<<dim3((M_TRAIN + 127) / 128), dim3(256), 0, stream>>>(tes, bimg, keyT);
    k_select  <<<dim3(128), dim3(256), 0, stream>>>(keyT, cand);
    k_refine  <<<dim3(128), dim3(256), 0, stream>>>(tes, conceptT, cand, psum);
    k_finalize<<<dim3(1),   dim3(128), 0, stream>>>(psum, out + 40962);
}

// Round 3
// 736.474 us; speedup vs baseline: 1.4089x; 1.1985x over previous
//
#include <hip/hip_runtime.h>
#include <stdint.h>

#define M_TRAIN 100000
#define D_DIM   768
#define C_DIM   128
#define NCLUST  500
#define CSIZE   100
#define NCLS    10
#define KSEL    10
#define NCHUNK  4
#define CHUNKN  25000
#define CAND_PER 16
#define NCT     (NCHUNK * CAND_PER)   // 64 candidates per concept
#define FLT_INF 3.402823466e38f

typedef __attribute__((ext_vector_type(8))) short bhalf8;
typedef __attribute__((ext_vector_type(4))) float f32x4;
typedef __attribute__((ext_vector_type(8))) unsigned short ushort8;
typedef __attribute__((ext_vector_type(4))) unsigned short ushort4v;

// ws layout (bytes)
#define WS_KEYT   0LL          // 128*100000*2 = 25,600,000 (bf16 keys)
#define WS_BIMG   25600000LL   // 768*128*2 = 196,608 (12 chunks x 16KB, pre-swizzled)
#define WS_CONT   25796608LL   // conceptT 128*768*4 = 393,216
#define WS_GRAM   26189824LL   // 128*128*4 = 65,536
#define WS_PSCORE 26255360LL   // 2*500*128*4 = 512,000
#define WS_CT     26767360LL   // 768*10*4 = 30,720
#define WS_CAND   26798080LL   // 128*64*4 = 32,768
#define WS_PSUM   26830848LL   // 128*4

static __device__ __forceinline__ unsigned short f2bf(float f) {
    union { float f; unsigned int u; } x; x.f = f;
    unsigned int u = x.u;
    return (unsigned short)((u + 0x7fffu + ((u >> 16) & 1u)) >> 16);
}

// ---------------- prep: conceptT (f32 transpose) + pre-swizzled bf16 B image ----------------
__global__ void k_prep(const float* __restrict__ cpt, float* __restrict__ conceptT,
                       unsigned short* __restrict__ bimg) {
    int tid = blockIdx.x * 256 + threadIdx.x;  // 0..98303
    int d = tid >> 7, c = tid & 127;
    float v = cpt[tid];
    conceptT[c * D_DIM + d] = v;
    int kc = d >> 6, kin = d & 63;
    int ofs = kc * 16384 + (((c << 7) + (kin << 1)) ^ ((c & 7) << 4));
    *(unsigned short*)((char*)bimg + ofs) = f2bf(v);
}

// ---------------- gram = conceptT @ concept (128x128) ----------------
__global__ void k_gram(const float* __restrict__ cpt, float* __restrict__ gram) {
    int c1 = blockIdx.x, c2 = threadIdx.x;
    float s = 0.f;
    #pragma unroll 4
    for (int d = 0; d < D_DIM; ++d)
        s += cpt[d * 128 + c1] * cpt[d * 128 + c2];
    gram[c1 * 128 + c2] = s;
}

// ---------------- single-block: L2new + unnormalized Gauss-Jordan (float4 chunks), ct = C@t --
// Thread t: row r = t&127, chunk-phase j = t>>7 (chunks c4 = j+4k). Pivot-row
// chunk is read right before its FMA; write/read pairs are same-row different-
// offset (provably disjoint) -> compiler can pipeline. Chunk-skip branches are
// wave-uniform (j uniform per wave). Straddle chunk handled by per-element
// c>p selects (rewrites identical bits below pivot -> benign).
#define STRW 164   // words per row; 41 float4s; 164%32=4 -> b128 banks tile evenly
__global__ void __launch_bounds__(512) k_solve(const float* __restrict__ gram,
        const float* __restrict__ whx, const float* __restrict__ cpt,
        const float* __restrict__ conceptT, float* __restrict__ ct,
        float* __restrict__ out_l2new) {
    __shared__ float aug[128 * STRW];    // cols 0..127 gram, 128..137 rhs
    __shared__ float tsol[128 * NCLS];
    __shared__ float red[512];
    int t = threadIdx.x;
    int r = t & 127, j = t >> 7;
    float part = 0.f;
    for (int i = t; i < 128 * 128; i += 512) {
        int rr = i >> 7, cc = i & 127;
        float g = gram[i];
        aug[rr * STRW + cc] = g;
        if (rr != cc) part += g;
    }
    // rhs[c][jj] = sum_d conceptT[c][d] * whx[jj][d]
    for (int o = t; o < 128 * NCLS; o += 512) {
        int cc = o / NCLS, jj = o - cc * NCLS;
        const float* cr = conceptT + cc * D_DIM;
        const float* wr = whx + jj * D_DIM;
        float s = 0.f;
        for (int d = 0; d < D_DIM; d += 4)
            s += cr[d]*wr[d] + cr[d+1]*wr[d+1] + cr[d+2]*wr[d+2] + cr[d+3]*wr[d+3];
        aug[cc * STRW + 128 + jj] = s;
    }
    red[t] = part;
    __syncthreads();
    for (int s = 256; s > 0; s >>= 1) { if (t < s) red[t] += red[t + s]; __syncthreads(); }
    if (t == 0) out_l2new[0] = red[0] / 16384.0f;

    for (int p = 0; p < 128; ++p) {
        __syncthreads();
        float diag = aug[p * STRW + p];
        float f = aug[r * STRW + p] / diag;
        bool act = (r != p);
        int dd = (p >> 2) - j;
        int k0 = dd <= 0 ? 0 : (dd + 3) >> 2;
        const float* prow = &aug[p * STRW];
        float* myrow = &aug[r * STRW];
        #pragma unroll
        for (int k = 0; k < 9; ++k) {
            int c4 = j + 4 * k;
            if (k >= k0 && c4 < 35) {          // wave-uniform
                if (act) {
                    int c0 = 4 * c4;
                    float4 pr = *(const float4*)(prow + c0);
                    float4 v  = *(float4*)(myrow + c0);
                    v.x = (c0 + 0 > p) ? v.x - f * pr.x : v.x;
                    v.y = (c0 + 1 > p) ? v.y - f * pr.y : v.y;
                    v.z = (c0 + 2 > p) ? v.z - f * pr.z : v.z;
                    v.w = (c0 + 3 > p) ? v.w - f * pr.w : v.w;
                    *(float4*)(myrow + c0) = v;
                }
            }
        }
    }
    __syncthreads();
    // t_sol = rhs / diag  (matrix is now diagonal)
    for (int o = t; o < 128 * NCLS; o += 512) {
        int cc = o / NCLS, jj = o - cc * NCLS;
        tsol[o] = aug[cc * STRW + 128 + jj] / aug[cc * STRW + cc];
    }
    __syncthreads();
    // ct[d][jj] = sum_c cpt[d][c] * t_sol[c][jj]
    for (int o = t; o < D_DIM * NCLS; o += 512) {
        int d = o / NCLS, jj = o - d * NCLS;
        const float* crow = cpt + d * 128;
        float s = 0.f;
        #pragma unroll 4
        for (int cc = 0; cc < 128; ++cc) s += crow[cc] * tsol[cc * NCLS + jj];
        ct[o] = s;
    }
}

// ---------------- y_pred = X @ ct + b (4096x10) ----------------
__global__ void k_ypred(const float* __restrict__ te, const float* __restrict__ ct,
                        const float* __restrict__ bhx, float* __restrict__ out) {
    __shared__ float ctT[NCLS][D_DIM];
    int t = threadIdx.x;
    for (int o = t; o < D_DIM * NCLS; o += 256) {
        int j = o / D_DIM, d = o % D_DIM;
        ctT[j][d] = ct[d * NCLS + j];
    }
    __syncthreads();
    int r = t >> 5, l = t & 31;
    long row = (long)blockIdx.x * 8 + r;
    const float* er = te + row * D_DIM;
    float acc[NCLS];
    #pragma unroll
    for (int j = 0; j < NCLS; ++j) acc[j] = 0.f;
    for (int d0 = l * 4; d0 < D_DIM; d0 += 128) {
        float4 e = *(const float4*)(er + d0);
        #pragma unroll
        for (int j = 0; j < NCLS; ++j) {
            float4 cc = *(const float4*)(&ctT[j][d0]);
            acc[j] += e.x*cc.x + e.y*cc.y + e.z*cc.z + e.w*cc.w;
        }
    }
    #pragma unroll
    for (int j = 0; j < NCLS; ++j) {
        #pragma unroll
        for (int m = 16; m > 0; m >>= 1) acc[j] += __shfl_xor(acc[j], m);
    }
    if (l == 0) {
        #pragma unroll
        for (int j = 0; j < NCLS; ++j) out[row * NCLS + j] = acc[j] + bhx[j];
    }
}

// ---------------- partial cluster mean-dot: pscore[h][cl][c] (raw, no abs/norm) -------------
__global__ void __launch_bounds__(192) k_score(const float* __restrict__ clus,
        const float* __restrict__ cpt, float* __restrict__ pscore) {
    __shared__ float mean_s[D_DIM];
    int cl = blockIdx.x >> 1, h = blockIdx.x & 1;
    int t = threadIdx.x;
    const float* base = clus + (long)cl * CSIZE * D_DIM + (long)h * 50 * D_DIM + t * 4;
    float ax = 0.f, ay = 0.f, az = 0.f, aw = 0.f;
    for (int s = 0; s < 50; s += 2) {
        float4 v0 = *(const float4*)(base + (long)s * D_DIM);
        float4 v1 = *(const float4*)(base + (long)(s + 1) * D_DIM);
        ax += v0.x + v1.x; ay += v0.y + v1.y;
        az += v0.z + v1.z; aw += v0.w + v1.w;
    }
    const float k = 1.0f / CSIZE;
    mean_s[t * 4 + 0] = ax * k; mean_s[t * 4 + 1] = ay * k;
    mean_s[t * 4 + 2] = az * k; mean_s[t * 4 + 3] = aw * k;
    __syncthreads();
    if (t < 128) {
        float s = 0.f;
        #pragma unroll 4
        for (int d = 0; d < D_DIM; ++d) s += mean_s[d] * cpt[d * 128 + t];
        pscore[h * (NCLUST * 128) + cl * 128 + t] = s;
    }
}

// ---------------- L1old, L2old from pscore halves ----------------
__global__ void __launch_bounds__(1024) k_old(const float* __restrict__ pscore,
        const float* __restrict__ gram, float* __restrict__ out01) {
    __shared__ float ss8[8][128];
    __shared__ float sm8[8][128];
    __shared__ float rcn_s[128];
    __shared__ float wcomb[128];
    __shared__ float redA[128];
    __shared__ float redB[128];
    __shared__ float wred[16];
    __shared__ float trace_tot_s;
    const float* p0 = pscore;
    const float* p1 = pscore + NCLUST * 128;
    int t = threadIdx.x;
    if (t < 128) rcn_s[t] = 1.0f / fmaxf(sqrtf(gram[t * 129]), 1e-12f);
    __syncthreads();
    int c = t & 127, w8 = t >> 7;
    float rc = rcn_s[c];
    float ss = 0.f, sm = 0.f;
    for (int cl = w8; cl < NCLUST; cl += 8) {
        float v = fabsf(p0[cl * 128 + c] + p1[cl * 128 + c]) * rc;
        ss += v * v; sm += v;
    }
    ss8[w8][c] = ss; sm8[w8][c] = sm;
    __syncthreads();
    if (t < 128) {
        float S = 0.f, M = 0.f;
        #pragma unroll
        for (int i = 0; i < 8; ++i) { S += ss8[i][t]; M += sm8[i][t]; }
        float nn = fmaxf(sqrtf(S), 1e-12f);
        float iv = 1.0f / nn;
        wcomb[t] = rcn_s[t] * iv;
        redA[t] = M * iv;
        redB[t] = S * iv * iv;
    }
    __syncthreads();
    if (t < 64) {
        float a = redA[t] + redA[t + 64];
        float b = redB[t] + redB[t + 64];
        #pragma unroll
        for (int m = 32; m > 0; m >>= 1) { a += __shfl_xor(a, m); b += __shfl_xor(b, m); }
        if (t == 0) { out01[0] = a; trace_tot_s = b; }
    }
    __syncthreads();
    int w = t >> 6, lane = t & 63;
    float rsq = 0.f;
    for (int cl = w; cl < NCLUST; cl += 16) {
        float v = fabsf(p0[cl * 128 + lane] + p1[cl * 128 + lane]) * wcomb[lane]
                + fabsf(p0[cl * 128 + 64 + lane] + p1[cl * 128 + 64 + lane]) * wcomb[64 + lane];
        #pragma unroll
        for (int m = 32; m > 0; m >>= 1) v += __shfl_xor(v, m);
        if (lane == 0) rsq += v * v;
    }
    if (lane == 0) wred[w] = rsq;
    __syncthreads();
    if (t == 0) {
        float s = 0.f;
        for (int i = 0; i < 16; ++i) s += wred[i];
        out01[1] = s - trace_tot_s;
    }
}

// ---------------- big MFMA: keyT[c][n] = bf16(e_sq[n] - 2*(E@C)[n][c]) ----------------
__global__ void __launch_bounds__(256) k_P(const float* __restrict__ E,
        const unsigned short* __restrict__ bimg, unsigned short* __restrict__ keyT) {
    __shared__ unsigned short Alds[128 * 64];  // [row][k] bf16, XOR-swizzled
    __shared__ unsigned short Blds[128 * 64];  // [c][k]  bf16, XOR-swizzled (prebaked)
    __shared__ float esq_s[128];
    int t = threadIdx.x;
    int rowbase = blockIdx.x * 128;
    int lane = t & 63, w = t >> 6;
    int wr = w >> 1, wc = w & 1;
    const f32x4 vzero = {0.f, 0.f, 0.f, 0.f};
    f32x4 acc[4][4];
    #pragma unroll
    for (int m = 0; m < 4; ++m)
        #pragma unroll
        for (int n = 0; n < 4; ++n) acc[m][n] = vzero;
    float esq_p[4] = {0.f, 0.f, 0.f, 0.f};
    char* Ab = (char*)Alds;
    char* Bb = (char*)Blds;
    int g = t >> 3, k8 = t & 7;

    for (int ks = 0; ks < 12; ++ks) {
        // stage A (f32 -> bf16, fused e_sq)
        #pragma unroll
        for (int p = 0; p < 4; ++p) {
            int row = 32 * p + g;
            int grow = rowbase + row;
            float4 v0 = {0.f,0.f,0.f,0.f}, v1 = {0.f,0.f,0.f,0.f};
            if (grow < M_TRAIN) {
                const float* src = E + (long)grow * D_DIM + ks * 64 + k8 * 8;
                v0 = *(const float4*)(src);
                v1 = *(const float4*)(src + 4);
            }
            esq_p[p] += v0.x*v0.x + v0.y*v0.y + v0.z*v0.z + v0.w*v0.w
                      + v1.x*v1.x + v1.y*v1.y + v1.z*v1.z + v1.w*v1.w;
            bhalf8 h;
            h[0] = (short)f2bf(v0.x); h[1] = (short)f2bf(v0.y);
            h[2] = (short)f2bf(v0.z); h[3] = (short)f2bf(v0.w);
            h[4] = (short)f2bf(v1.x); h[5] = (short)f2bf(v1.y);
            h[6] = (short)f2bf(v1.z); h[7] = (short)f2bf(v1.w);
            int byte = (row * 128 + k8 * 16) ^ ((row & 7) << 4);
            *(bhalf8*)(Ab + byte) = h;
        }
        // stage B: linear 16KB copy (pre-swizzled in global)
        {
            const char* src = (const char*)bimg + ks * 16384;
            #pragma unroll
            for (int i = 0; i < 4; ++i) {
                int idx = i * 256 + t;
                *(bhalf8*)(Bb + idx * 16) = *(const bhalf8*)(src + idx * 16);
            }
        }
        __syncthreads();
        bhalf8 af[4][2], bf[4][2];
        int kb = (lane >> 4) * 16;
        #pragma unroll
        for (int m = 0; m < 4; ++m) {
            int row = wr * 64 + m * 16 + (lane & 15);
            int b0 = row * 128, sw = (row & 7) << 4;
            af[m][0] = *(const bhalf8*)(Ab + ((b0 + kb) ^ sw));
            af[m][1] = *(const bhalf8*)(Ab + ((b0 + kb + 64) ^ sw));
        }
        #pragma unroll
        for (int n = 0; n < 4; ++n) {
            int c = wc * 64 + n * 16 + (lane & 15);
            int b0 = c * 128, sw = (c & 7) << 4;
            bf[n][0] = *(const bhalf8*)(Bb + ((b0 + kb) ^ sw));
            bf[n][1] = *(const bhalf8*)(Bb + ((b0 + kb + 64) ^ sw));
        }
        #pragma unroll
        for (int m = 0; m < 4; ++m)
            #pragma unroll
            for (int n = 0; n < 4; ++n) {
                acc[m][n] = __builtin_amdgcn_mfma_f32_16x16x32_bf16(af[m][0], bf[n][0], acc[m][n], 0, 0, 0);
                acc[m][n] = __builtin_amdgcn_mfma_f32_16x16x32_bf16(af[m][1], bf[n][1], acc[m][n], 0, 0, 0);
            }
        __syncthreads();
    }
    #pragma unroll
    for (int p = 0; p < 4; ++p) {
        float v = esq_p[p];
        v += __shfl_xor(v, 1); v += __shfl_xor(v, 2); v += __shfl_xor(v, 4);
        if (k8 == 0) esq_s[32 * p + g] = v;
    }
    __syncthreads();
    #pragma unroll
    for (int m = 0; m < 4; ++m) {
        int r0 = wr * 64 + m * 16 + (lane >> 4) * 4;
        if (rowbase + r0 >= M_TRAIN) continue;
        float e0 = esq_s[r0], e1 = esq_s[r0 + 1], e2 = esq_s[r0 + 2], e3 = esq_s[r0 + 3];
        #pragma unroll
        for (int n = 0; n < 4; ++n) {
            int c = wc * 64 + n * 16 + (lane & 15);
            ushort4v kv;
            kv[0] = f2bf(e0 - 2.f * acc[m][n][0]);
            kv[1] = f2bf(e1 - 2.f * acc[m][n][1]);
            kv[2] = f2bf(e2 - 2.f * acc[m][n][2]);
            kv[3] = f2bf(e3 - 2.f * acc[m][n][3]);
            *(ushort4v*)(keyT + (long)c * M_TRAIN + rowbase + r0) = kv;
        }
    }
}

// ---------------- per-(concept, quarter) approximate top-16 (bf16 keys, uint16 order) --------
__global__ void __launch_bounds__(256) k_select(const unsigned short* __restrict__ keyT,
                                                int* __restrict__ cand) {
    __shared__ int sk[2048];
    __shared__ int si[2048];
    __shared__ int wk[4]; __shared__ int wi[4], wsl[4];
    int c = blockIdx.x >> 2, h = blockIdx.x & 3;
    int t = threadIdx.x;
    const unsigned short* col = keyT + (long)c * M_TRAIN + h * CHUNKN;
    int base = h * CHUNKN;
    int tk[8], ti[8];
    #pragma unroll
    for (int i = 0; i < 8; ++i) { tk[i] = 0x7fffffff; ti[i] = 0x7fffffff; }
    for (int i = t; i < CHUNKN / 8; i += 256) {
        ushort8 v = *(const ushort8*)(col + i * 8);
        int idx = base + i * 8;
        #pragma unroll
        for (int q = 0; q < 8; ++q) {
            int cv = (int)v[q]; int ci = idx + q;
            if (cv < tk[7] || (cv == tk[7] && ci < ti[7])) {
                #pragma unroll
                for (int jj = 0; jj < 8; ++jj) {
                    bool sw = (cv < tk[jj]) || (cv == tk[jj] && ci < ti[jj]);
                    int ok = tk[jj]; int oi = ti[jj];
                    if (sw) { tk[jj] = cv; ti[jj] = ci; cv = ok; ci = oi; }
                }
            }
        }
    }
    #pragma unroll
    for (int i = 0; i < 8; ++i) { sk[t * 8 + i] = tk[i]; si[t * 8 + i] = ti[i]; }
    __syncthreads();
    int lane = t & 63, w = t >> 6;
    for (int sel = 0; sel < CAND_PER; ++sel) {
        int bk = 0x7fffffff, bi = 0x7fffffff, bs = -1;
        #pragma unroll
        for (int i = 0; i < 8; ++i) {
            int s = t * 8 + i;
            int v = sk[s];
            if (v < bk || (v == bk && si[s] < bi)) { bk = v; bi = si[s]; bs = s; }
        }
        #pragma unroll
        for (int m = 32; m > 0; m >>= 1) {
            int ok = __shfl_xor(bk, m); int oi = __shfl_xor(bi, m); int os = __shfl_xor(bs, m);
            if (ok < bk || (ok == bk && oi < bi)) { bk = ok; bi = oi; bs = os; }
        }
        if (lane == 0) { wk[w] = bk; wi[w] = bi; wsl[w] = bs; }
        __syncthreads();
        if (t == 0) {
            int fk = wk[0], fi = wi[0], fs = wsl[0];
            for (int i = 1; i < 4; ++i)
                if (wk[i] < fk || (wk[i] == fk && wi[i] < fi)) { fk = wk[i]; fi = wi[i]; fs = wsl[i]; }
            cand[(c * NCHUNK + h) * CAND_PER + sel] = fi;
            sk[fs] = 0x7fffffff; si[fs] = 0x7fffffff;
        }
        __syncthreads();
    }
}

// ---------------- exact f32 re-rank of 64 candidates, sum top-10 dots ----------------
__global__ void __launch_bounds__(512) k_refine(const float* __restrict__ E,
        const float* __restrict__ conceptT, const int* __restrict__ cand,
        float* __restrict__ psum) {
    __shared__ float skey[NCT], sdot[NCT];
    __shared__ int sidx[NCT];
    int c = blockIdx.x, t = threadIdx.x;
    int g = t >> 3, l8 = t & 7;
    int idx = cand[c * NCT + g];
    const float* er = E + (long)idx * D_DIM;
    const float* cr = conceptT + c * D_DIM;
    float dot = 0.f, ss = 0.f;
    for (int d0 = l8 * 4; d0 < D_DIM; d0 += 32) {
        float4 e = *(const float4*)(er + d0);
        float4 cc = *(const float4*)(cr + d0);
        dot += e.x*cc.x + e.y*cc.y + e.z*cc.z + e.w*cc.w;
        ss  += e.x*e.x + e.y*e.y + e.z*e.z + e.w*e.w;
    }
    dot += __shfl_xor(dot, 1); dot += __shfl_xor(dot, 2); dot += __shfl_xor(dot, 4);
    ss  += __shfl_xor(ss, 1);  ss  += __shfl_xor(ss, 2);  ss  += __shfl_xor(ss, 4);
    if (l8 == 0) { skey[g] = ss - 2.f * dot; sdot[g] = dot; sidx[g] = idx; }
    __syncthreads();
    if (t == 0) {
        float sum = 0.f;
        unsigned long long used = 0ull;
        for (int s = 0; s < KSEL; ++s) {
            float bk = FLT_INF; int bi = 0x7fffffff, bs = 0;
            for (int i = 0; i < NCT; ++i) {
                if ((used >> i) & 1ull) continue;
                if (skey[i] < bk || (skey[i] == bk && sidx[i] < bi)) { bk = skey[i]; bi = sidx[i]; bs = i; }
            }
            used |= (1ull << bs);
            sum += sdot[bs];
        }
        psum[c] = sum;
    }
}

__global__ void k_finalize(const float* __restrict__ psum, float* __restrict__ out2) {
    __shared__ float red[128];
    int t = threadIdx.x;
    red[t] = psum[t];
    __syncthreads();
    for (int s = 64; s > 0; s >>= 1) { if (t < s) red[t] += red[t + s]; __syncthreads(); }
    if (t == 0) out2[0] = red[0] * (1.0f / (C_DIM * KSEL));
}

extern "C" void kernel_launch(void* const* d_in, const int* in_sizes, int n_in,
                              void* d_out, int out_size, void* d_ws, size_t ws_size,
                              hipStream_t stream) {
    (void)in_sizes; (void)n_in; (void)out_size; (void)ws_size;
    const float* te   = (const float*)d_in[0];  // 4096x768
    const float* cpt  = (const float*)d_in[1];  // 768x128
    const float* clus = (const float*)d_in[2];  // 500x100x768
    const float* tes  = (const float*)d_in[3];  // 100000x768
    const float* whx  = (const float*)d_in[4];  // 10x768
    const float* bhx  = (const float*)d_in[5];  // 10
    float* out = (float*)d_out;                 // 40960 y_pred + 4 scalars
    char* ws = (char*)d_ws;
    unsigned short* keyT  = (unsigned short*)(ws + WS_KEYT);
    unsigned short* bimg  = (unsigned short*)(ws + WS_BIMG);
    float* conceptT       = (float*)(ws + WS_CONT);
    float* gram           = (float*)(ws + WS_GRAM);
    float* pscore         = (float*)(ws + WS_PSCORE);
    float* ct             = (float*)(ws + WS_CT);
    int* cand             = (int*)(ws + WS_CAND);
    float* psum           = (float*)(ws + WS_PSUM);

    k_prep    <<<dim3(384), dim3(256), 0, stream>>>(cpt, conceptT, bimg);
    k_gram    <<<dim3(128), dim3(128), 0, stream>>>(cpt, gram);
    k_solve   <<<dim3(1),   dim3(512), 0, stream>>>(gram, whx, cpt, conceptT, ct, out + 40963);
    k_ypred   <<<dim3(512), dim3(256), 0, stream>>>(te, ct, bhx, out);
    k_score   <<<dim3(1000),dim3(192), 0, stream>>>(clus, cpt, pscore);
    k_old     <<<dim3(1),   dim3(1024),0, stream>>>(pscore, gram, out + 40960);
    k_P       <<<dim3((M_TRAIN + 127) / 128), dim3(256), 0, stream>>>(tes, bimg, keyT);
    k_select  <<<dim3(128 * NCHUNK), dim3(256), 0, stream>>>(keyT, cand);
    k_refine  <<<dim3(128), dim3(512), 0, stream>>>(tes, conceptT, cand, psum);
    k_finalize<<<dim3(1),   dim3(128), 0, stream>>>(psum, out + 40962);
}

// Round 4
// 507.862 us; speedup vs baseline: 2.0431x; 1.4501x over previous
//
#include <hip/hip_runtime.h>
#include <stdint.h>

#define M_TRAIN 100000
#define D_DIM   768
#define C_DIM   128
#define NCLUST  500
#define CSIZE   100
#define NCLS    10
#define KSEL    10
#define NCHUNK  4
#define CHUNKN  25000
#define CAND_PER 16
#define NCT     (NCHUNK * CAND_PER)   // 64 candidates per concept
#define FLT_INF 3.402823466e38f

typedef __attribute__((ext_vector_type(8))) short bhalf8;
typedef __attribute__((ext_vector_type(4))) float f32x4;
typedef __attribute__((ext_vector_type(8))) unsigned short ushort8;
typedef __attribute__((ext_vector_type(4))) unsigned short ushort4v;

// ws layout (bytes)
#define WS_KEYT   0LL          // 128*100000*2 = 25,600,000 (bf16 keys)
#define WS_BIMG   25600000LL   // 768*128*2 = 196,608 (12 chunks x 16KB, pre-swizzled)
#define WS_CONT   25796608LL   // conceptT 128*768*4 = 393,216
#define WS_GRAM   26189824LL   // 128*128*4 = 65,536
#define WS_PSCORE 26255360LL   // 2*500*128*4 = 512,000
#define WS_CT     26767360LL   // 768*10*4 = 30,720
#define WS_CAND   26798080LL   // 128*64*4 = 32,768
#define WS_PSUM   26830848LL   // 128*4
#define WS_TSOL   26831360LL   // 128*10*4 = 5,120

static __device__ __forceinline__ unsigned short f2bf(float f) {
    union { float f; unsigned int u; } x; x.f = f;
    unsigned int u = x.u;
    return (unsigned short)((u + 0x7fffu + ((u >> 16) & 1u)) >> 16);
}

// ---------------- prep: conceptT (f32 transpose) + pre-swizzled bf16 B image ----------------
__global__ void k_prep(const float* __restrict__ cpt, float* __restrict__ conceptT,
                       unsigned short* __restrict__ bimg) {
    int tid = blockIdx.x * 256 + threadIdx.x;  // 0..98303
    int d = tid >> 7, c = tid & 127;
    float v = cpt[tid];
    conceptT[c * D_DIM + d] = v;
    int kc = d >> 6, kin = d & 63;
    int ofs = kc * 16384 + (((c << 7) + (kin << 1)) ^ ((c & 7) << 4));
    *(unsigned short*)((char*)bimg + ofs) = f2bf(v);
}

// ---------------- gram = conceptT @ concept (128x128) ----------------
__global__ void k_gram(const float* __restrict__ cpt, float* __restrict__ gram) {
    int c1 = blockIdx.x, c2 = threadIdx.x;
    float s = 0.f;
    #pragma unroll 4
    for (int d = 0; d < D_DIM; ++d)
        s += cpt[d * 128 + c1] * cpt[d * 128 + c2];
    gram[c1 * 128 + c2] = s;
}

// ---------------- L_sparse_2_new = (sum(gram) - trace(gram)) / 16384 ----------------
__global__ void __launch_bounds__(128) k_l2new(const float* __restrict__ gram,
                                               float* __restrict__ out_l2new) {
    __shared__ float rbuf[2];
    int t = threadIdx.x;
    float s = 0.f;
    #pragma unroll 8
    for (int c = 0; c < 128; c += 4) {
        float4 g = *(const float4*)&gram[t * 128 + c];
        s += g.x + g.y + g.z + g.w;
    }
    s -= gram[t * 129];
    #pragma unroll
    for (int m = 32; m > 0; m >>= 1) s += __shfl_xor(s, m);
    if ((t & 63) == 0) rbuf[t >> 6] = s;
    __syncthreads();
    if (t == 0) out_l2new[0] = (rbuf[0] + rbuf[1]) / 16384.0f;
}

// ---------------- CG solve: G t_j = (C^T W^T)_j, one block per RHS column j ----------------
// G is SPD Wishart-like, kappa ~ 5.7 -> 24 iters reach f32 floor. 3 light
// barriers per iter (2 waves) instead of 128 serial block-wide pivots.
#define GSTR 132   // LDS row stride in words; 132%32=4 -> b128 hits the 8-start-bank floor
__device__ __forceinline__ float blk_red2(float v, float* buf, int t) {
    #pragma unroll
    for (int m = 32; m > 0; m >>= 1) v += __shfl_xor(v, m);
    __syncthreads();                 // protect buf from previous round
    if ((t & 63) == 0) buf[t >> 6] = v;
    __syncthreads();
    return buf[0] + buf[1];
}

__global__ void __launch_bounds__(128) k_cg(const float* __restrict__ gram,
        const float* __restrict__ cpt, const float* __restrict__ whx,
        float* __restrict__ tsol) {
    __shared__ float G[128 * GSTR];
    __shared__ float p_s[128];
    __shared__ float rbuf[2];
    int j = blockIdx.x, t = threadIdx.x;      // t = row index r
    // rhs_r = sum_d cpt[d*128+r] * whx[j][d]  (coalesced across threads)
    const float* wj = whx + j * D_DIM;
    float rhs = 0.f;
    for (int d = 0; d < D_DIM; d += 4) {
        rhs += cpt[(d + 0) * 128 + t] * wj[d + 0]
             + cpt[(d + 1) * 128 + t] * wj[d + 1]
             + cpt[(d + 2) * 128 + t] * wj[d + 2]
             + cpt[(d + 3) * 128 + t] * wj[d + 3];
    }
    // stage G row t in LDS
    #pragma unroll 8
    for (int c = 0; c < 128; c += 4)
        *(float4*)&G[t * GSTR + c] = *(const float4*)&gram[t * 128 + c];
    float x = 0.f, res = rhs, p = rhs;
    p_s[t] = p;
    float rr = blk_red2(res * res, rbuf, t);
    __syncthreads();   // G + p_s visible
    for (int it = 0; it < 24; ++it) {
        // q_r = G[r][:] . p
        float q = 0.f;
        #pragma unroll 8
        for (int c = 0; c < 128; c += 4) {
            float4 g  = *(const float4*)&G[t * GSTR + c];
            float4 pp = *(const float4*)&p_s[c];     // broadcast
            q += g.x * pp.x + g.y * pp.y + g.z * pp.z + g.w * pp.w;
        }
        float pq = blk_red2(p * q, rbuf, t);
        float alpha = rr / pq;
        x += alpha * p;
        res -= alpha * q;
        float rrn = blk_red2(res * res, rbuf, t);
        float beta = rrn / rr;
        rr = rrn;
        p = res + beta * p;
        p_s[t] = p;        // all matvec reads of p_s completed before pq-reduce barriers
        __syncthreads();
    }
    tsol[t * NCLS + j] = x;
}

// ---------------- ct[d][j] = sum_c cpt[d][c] * tsol[c][j] ----------------
__global__ void __launch_bounds__(256) k_ct(const float* __restrict__ cpt,
        const float* __restrict__ tsol, float* __restrict__ ct) {
    int idx = blockIdx.x * 256 + threadIdx.x;   // 0..7679
    int d = idx / NCLS, j = idx - d * NCLS;
    const float* crow = cpt + d * 128;
    float s = 0.f;
    #pragma unroll 4
    for (int c = 0; c < 128; ++c) s += crow[c] * tsol[c * NCLS + j];
    ct[idx] = s;
}

// ---------------- y_pred = X @ ct + b (4096x10) ----------------
__global__ void k_ypred(const float* __restrict__ te, const float* __restrict__ ct,
                        const float* __restrict__ bhx, float* __restrict__ out) {
    __shared__ float ctT[NCLS][D_DIM];
    int t = threadIdx.x;
    for (int o = t; o < D_DIM * NCLS; o += 256) {
        int j = o / D_DIM, d = o % D_DIM;
        ctT[j][d] = ct[d * NCLS + j];
    }
    __syncthreads();
    int r = t >> 5, l = t & 31;
    long row = (long)blockIdx.x * 8 + r;
    const float* er = te + row * D_DIM;
    float acc[NCLS];
    #pragma unroll
    for (int j = 0; j < NCLS; ++j) acc[j] = 0.f;
    for (int d0 = l * 4; d0 < D_DIM; d0 += 128) {
        float4 e = *(const float4*)(er + d0);
        #pragma unroll
        for (int j = 0; j < NCLS; ++j) {
            float4 cc = *(const float4*)(&ctT[j][d0]);
            acc[j] += e.x*cc.x + e.y*cc.y + e.z*cc.z + e.w*cc.w;
        }
    }
    #pragma unroll
    for (int j = 0; j < NCLS; ++j) {
        #pragma unroll
        for (int m = 16; m > 0; m >>= 1) acc[j] += __shfl_xor(acc[j], m);
    }
    if (l == 0) {
        #pragma unroll
        for (int j = 0; j < NCLS; ++j) out[row * NCLS + j] = acc[j] + bhx[j];
    }
}

// ---------------- partial cluster mean-dot: pscore[h][cl][c] (raw, no abs/norm) -------------
__global__ void __launch_bounds__(192) k_score(const float* __restrict__ clus,
        const float* __restrict__ cpt, float* __restrict__ pscore) {
    __shared__ float mean_s[D_DIM];
    int cl = blockIdx.x >> 1, h = blockIdx.x & 1;
    int t = threadIdx.x;
    const float* base = clus + (long)cl * CSIZE * D_DIM + (long)h * 50 * D_DIM + t * 4;
    float ax = 0.f, ay = 0.f, az = 0.f, aw = 0.f;
    for (int s = 0; s < 50; s += 2) {
        float4 v0 = *(const float4*)(base + (long)s * D_DIM);
        float4 v1 = *(const float4*)(base + (long)(s + 1) * D_DIM);
        ax += v0.x + v1.x; ay += v0.y + v1.y;
        az += v0.z + v1.z; aw += v0.w + v1.w;
    }
    const float k = 1.0f / CSIZE;
    mean_s[t * 4 + 0] = ax * k; mean_s[t * 4 + 1] = ay * k;
    mean_s[t * 4 + 2] = az * k; mean_s[t * 4 + 3] = aw * k;
    __syncthreads();
    if (t < 128) {
        float s = 0.f;
        #pragma unroll 4
        for (int d = 0; d < D_DIM; ++d) s += mean_s[d] * cpt[d * 128 + t];
        pscore[h * (NCLUST * 128) + cl * 128 + t] = s;
    }
}

// ---------------- L1old, L2old from pscore halves ----------------
__global__ void __launch_bounds__(1024) k_old(const float* __restrict__ pscore,
        const float* __restrict__ gram, float* __restrict__ out01) {
    __shared__ float ss8[8][128];
    __shared__ float sm8[8][128];
    __shared__ float rcn_s[128];
    __shared__ float wcomb[128];
    __shared__ float redA[128];
    __shared__ float redB[128];
    __shared__ float wred[16];
    __shared__ float trace_tot_s;
    const float* p0 = pscore;
    const float* p1 = pscore + NCLUST * 128;
    int t = threadIdx.x;
    if (t < 128) rcn_s[t] = 1.0f / fmaxf(sqrtf(gram[t * 129]), 1e-12f);
    __syncthreads();
    int c = t & 127, w8 = t >> 7;
    float rc = rcn_s[c];
    float ss = 0.f, sm = 0.f;
    for (int cl = w8; cl < NCLUST; cl += 8) {
        float v = fabsf(p0[cl * 128 + c] + p1[cl * 128 + c]) * rc;
        ss += v * v; sm += v;
    }
    ss8[w8][c] = ss; sm8[w8][c] = sm;
    __syncthreads();
    if (t < 128) {
        float S = 0.f, M = 0.f;
        #pragma unroll
        for (int i = 0; i < 8; ++i) { S += ss8[i][t]; M += sm8[i][t]; }
        float nn = fmaxf(sqrtf(S), 1e-12f);
        float iv = 1.0f / nn;
        wcomb[t] = rcn_s[t] * iv;
        redA[t] = M * iv;
        redB[t] = S * iv * iv;
    }
    __syncthreads();
    if (t < 64) {
        float a = redA[t] + redA[t + 64];
        float b = redB[t] + redB[t + 64];
        #pragma unroll
        for (int m = 32; m > 0; m >>= 1) { a += __shfl_xor(a, m); b += __shfl_xor(b, m); }
        if (t == 0) { out01[0] = a; trace_tot_s = b; }
    }
    __syncthreads();
    int w = t >> 6, lane = t & 63;
    float rsq = 0.f;
    for (int cl = w; cl < NCLUST; cl += 16) {
        float v = fabsf(p0[cl * 128 + lane] + p1[cl * 128 + lane]) * wcomb[lane]
                + fabsf(p0[cl * 128 + 64 + lane] + p1[cl * 128 + 64 + lane]) * wcomb[64 + lane];
        #pragma unroll
        for (int m = 32; m > 0; m >>= 1) v += __shfl_xor(v, m);
        if (lane == 0) rsq += v * v;
    }
    if (lane == 0) wred[w] = rsq;
    __syncthreads();
    if (t == 0) {
        float s = 0.f;
        for (int i = 0; i < 16; ++i) s += wred[i];
        out01[1] = s - trace_tot_s;
    }
}

// ---------------- big MFMA: keyT[c][n] = bf16(e_sq[n] - 2*(E@C)[n][c]) ----------------
__global__ void __launch_bounds__(256) k_P(const float* __restrict__ E,
        const unsigned short* __restrict__ bimg, unsigned short* __restrict__ keyT) {
    __shared__ unsigned short Alds[128 * 64];  // [row][k] bf16, XOR-swizzled
    __shared__ unsigned short Blds[128 * 64];  // [c][k]  bf16, XOR-swizzled (prebaked)
    __shared__ float esq_s[128];
    int t = threadIdx.x;
    int rowbase = blockIdx.x * 128;
    int lane = t & 63, w = t >> 6;
    int wr = w >> 1, wc = w & 1;
    const f32x4 vzero = {0.f, 0.f, 0.f, 0.f};
    f32x4 acc[4][4];
    #pragma unroll
    for (int m = 0; m < 4; ++m)
        #pragma unroll
        for (int n = 0; n < 4; ++n) acc[m][n] = vzero;
    float esq_p[4] = {0.f, 0.f, 0.f, 0.f};
    char* Ab = (char*)Alds;
    char* Bb = (char*)Blds;
    int g = t >> 3, k8 = t & 7;

    for (int ks = 0; ks < 12; ++ks) {
        // stage A (f32 -> bf16, fused e_sq)
        #pragma unroll
        for (int p = 0; p < 4; ++p) {
            int row = 32 * p + g;
            int grow = rowbase + row;
            float4 v0 = {0.f,0.f,0.f,0.f}, v1 = {0.f,0.f,0.f,0.f};
            if (grow < M_TRAIN) {
                const float* src = E + (long)grow * D_DIM + ks * 64 + k8 * 8;
                v0 = *(const float4*)(src);
                v1 = *(const float4*)(src + 4);
            }
            esq_p[p] += v0.x*v0.x + v0.y*v0.y + v0.z*v0.z + v0.w*v0.w
                      + v1.x*v1.x + v1.y*v1.y + v1.z*v1.z + v1.w*v1.w;
            bhalf8 h;
            h[0] = (short)f2bf(v0.x); h[1] = (short)f2bf(v0.y);
            h[2] = (short)f2bf(v0.z); h[3] = (short)f2bf(v0.w);
            h[4] = (short)f2bf(v1.x); h[5] = (short)f2bf(v1.y);
            h[6] = (short)f2bf(v1.z); h[7] = (short)f2bf(v1.w);
            int byte = (row * 128 + k8 * 16) ^ ((row & 7) << 4);
            *(bhalf8*)(Ab + byte) = h;
        }
        // stage B: linear 16KB copy (pre-swizzled in global)
        {
            const char* src = (const char*)bimg + ks * 16384;
            #pragma unroll
            for (int i = 0; i < 4; ++i) {
                int idx = i * 256 + t;
                *(bhalf8*)(Bb + idx * 16) = *(const bhalf8*)(src + idx * 16);
            }
        }
        __syncthreads();
        bhalf8 af[4][2], bf[4][2];
        int kb = (lane >> 4) * 16;
        #pragma unroll
        for (int m = 0; m < 4; ++m) {
            int row = wr * 64 + m * 16 + (lane & 15);
            int b0 = row * 128, sw = (row & 7) << 4;
            af[m][0] = *(const bhalf8*)(Ab + ((b0 + kb) ^ sw));
            af[m][1] = *(const bhalf8*)(Ab + ((b0 + kb + 64) ^ sw));
        }
        #pragma unroll
        for (int n = 0; n < 4; ++n) {
            int c = wc * 64 + n * 16 + (lane & 15);
            int b0 = c * 128, sw = (c & 7) << 4;
            bf[n][0] = *(const bhalf8*)(Bb + ((b0 + kb) ^ sw));
            bf[n][1] = *(const bhalf8*)(Bb + ((b0 + kb + 64) ^ sw));
        }
        #pragma unroll
        for (int m = 0; m < 4; ++m)
            #pragma unroll
            for (int n = 0; n < 4; ++n) {
                acc[m][n] = __builtin_amdgcn_mfma_f32_16x16x32_bf16(af[m][0], bf[n][0], acc[m][n], 0, 0, 0);
                acc[m][n] = __builtin_amdgcn_mfma_f32_16x16x32_bf16(af[m][1], bf[n][1], acc[m][n], 0, 0, 0);
            }
        __syncthreads();
    }
    #pragma unroll
    for (int p = 0; p < 4; ++p) {
        float v = esq_p[p];
        v += __shfl_xor(v, 1); v += __shfl_xor(v, 2); v += __shfl_xor(v, 4);
        if (k8 == 0) esq_s[32 * p + g] = v;
    }
    __syncthreads();
    #pragma unroll
    for (int m = 0; m < 4; ++m) {
        int r0 = wr * 64 + m * 16 + (lane >> 4) * 4;
        if (rowbase + r0 >= M_TRAIN) continue;
        float e0 = esq_s[r0], e1 = esq_s[r0 + 1], e2 = esq_s[r0 + 2], e3 = esq_s[r0 + 3];
        #pragma unroll
        for (int n = 0; n < 4; ++n) {
            int c = wc * 64 + n * 16 + (lane & 15);
            ushort4v kv;
            kv[0] = f2bf(e0 - 2.f * acc[m][n][0]);
            kv[1] = f2bf(e1 - 2.f * acc[m][n][1]);
            kv[2] = f2bf(e2 - 2.f * acc[m][n][2]);
            kv[3] = f2bf(e3 - 2.f * acc[m][n][3]);
            *(ushort4v*)(keyT + (long)c * M_TRAIN + rowbase + r0) = kv;
        }
    }
}

// ---------------- per-(concept, quarter) approximate top-16 (bf16 keys, uint16 order) --------
__global__ void __launch_bounds__(256) k_select(const unsigned short* __restrict__ keyT,
                                                int* __restrict__ cand) {
    __shared__ int sk[2048];
    __shared__ int si[2048];
    __shared__ int wk[4]; __shared__ int wi[4], wsl[4];
    int c = blockIdx.x >> 2, h = blockIdx.x & 3;
    int t = threadIdx.x;
    const unsigned short* col = keyT + (long)c * M_TRAIN + h * CHUNKN;
    int base = h * CHUNKN;
    int tk[8], ti[8];
    #pragma unroll
    for (int i = 0; i < 8; ++i) { tk[i] = 0x7fffffff; ti[i] = 0x7fffffff; }
    for (int i = t; i < CHUNKN / 8; i += 256) {
        ushort8 v = *(const ushort8*)(col + i * 8);
        int idx = base + i * 8;
        #pragma unroll
        for (int q = 0; q < 8; ++q) {
            int cv = (int)v[q]; int ci = idx + q;
            if (cv < tk[7] || (cv == tk[7] && ci < ti[7])) {
                #pragma unroll
                for (int jj = 0; jj < 8; ++jj) {
                    bool sw = (cv < tk[jj]) || (cv == tk[jj] && ci < ti[jj]);
                    int ok = tk[jj]; int oi = ti[jj];
                    if (sw) { tk[jj] = cv; ti[jj] = ci; cv = ok; ci = oi; }
                }
            }
        }
    }
    #pragma unroll
    for (int i = 0; i < 8; ++i) { sk[t * 8 + i] = tk[i]; si[t * 8 + i] = ti[i]; }
    __syncthreads();
    int lane = t & 63, w = t >> 6;
    for (int sel = 0; sel < CAND_PER; ++sel) {
        int bk = 0x7fffffff, bi = 0x7fffffff, bs = -1;
        #pragma unroll
        for (int i = 0; i < 8; ++i) {
            int s = t * 8 + i;
            int v = sk[s];
            if (v < bk || (v == bk && si[s] < bi)) { bk = v; bi = si[s]; bs = s; }
        }
        #pragma unroll
        for (int m = 32; m > 0; m >>= 1) {
            int ok = __shfl_xor(bk, m); int oi = __shfl_xor(bi, m); int os = __shfl_xor(bs, m);
            if (ok < bk || (ok == bk && oi < bi)) { bk = ok; bi = oi; bs = os; }
        }
        if (lane == 0) { wk[w] = bk; wi[w] = bi; wsl[w] = bs; }
        __syncthreads();
        if (t == 0) {
            int fk = wk[0], fi = wi[0], fs = wsl[0];
            for (int i = 1; i < 4; ++i)
                if (wk[i] < fk || (wk[i] == fk && wi[i] < fi)) { fk = wk[i]; fi = wi[i]; fs = wsl[i]; }
            cand[(c * NCHUNK + h) * CAND_PER + sel] = fi;
            sk[fs] = 0x7fffffff; si[fs] = 0x7fffffff;
        }
        __syncthreads();
    }
}

// ---------------- exact f32 re-rank of 64 candidates, sum top-10 dots ----------------
__global__ void __launch_bounds__(512) k_refine(const float* __restrict__ E,
        const float* __restrict__ conceptT, const int* __restrict__ cand,
        float* __restrict__ psum) {
    __shared__ float skey[NCT], sdot[NCT];
    __shared__ int sidx[NCT];
    int c = blockIdx.x, t = threadIdx.x;
    int g = t >> 3, l8 = t & 7;
    int idx = cand[c * NCT + g];
    const float* er = E + (long)idx * D_DIM;
    const float* cr = conceptT + c * D_DIM;
    float dot = 0.f, ss = 0.f;
    for (int d0 = l8 * 4; d0 < D_DIM; d0 += 32) {
        float4 e = *(const float4*)(er + d0);
        float4 cc = *(const float4*)(cr + d0);
        dot += e.x*cc.x + e.y*cc.y + e.z*cc.z + e.w*cc.w;
        ss  += e.x*e.x + e.y*e.y + e.z*e.z + e.w*e.w;
    }
    dot += __shfl_xor(dot, 1); dot += __shfl_xor(dot, 2); dot += __shfl_xor(dot, 4);
    ss  += __shfl_xor(ss, 1);  ss  += __shfl_xor(ss, 2);  ss  += __shfl_xor(ss, 4);
    if (l8 == 0) { skey[g] = ss - 2.f * dot; sdot[g] = dot; sidx[g] = idx; }
    __syncthreads();
    if (t == 0) {
        float sum = 0.f;
        unsigned long long used = 0ull;
        for (int s = 0; s < KSEL; ++s) {
            float bk = FLT_INF; int bi = 0x7fffffff, bs = 0;
            for (int i = 0; i < NCT; ++i) {
                if ((used >> i) & 1ull) continue;
                if (skey[i] < bk || (skey[i] == bk && sidx[i] < bi)) { bk = skey[i]; bi = sidx[i]; bs = i; }
            }
            used |= (1ull << bs);
            sum += sdot[bs];
        }
        psum[c] = sum;
    }
}

__global__ void k_finalize(const float* __restrict__ psum, float* __restrict__ out2) {
    __shared__ float red[128];
    int t = threadIdx.x;
    red[t] = psum[t];
    __syncthreads();
    for (int s = 64; s > 0; s >>= 1) { if (t < s) red[t] += red[t + s]; __syncthreads(); }
    if (t == 0) out2[0] = red[0] * (1.0f / (C_DIM * KSEL));
}

extern "C" void kernel_launch(void* const* d_in, const int* in_sizes, int n_in,
                              void* d_out, int out_size, void* d_ws, size_t ws_size,
                              hipStream_t stream) {
    (void)in_sizes; (void)n_in; (void)out_size; (void)ws_size;
    const float* te   = (const float*)d_in[0];  // 4096x768
    const float* cpt  = (const float*)d_in[1];  // 768x128
    const float* clus = (const float*)d_in[2];  // 500x100x768
    const float* tes  = (const float*)d_in[3];  // 100000x768
    const float* whx  = (const float*)d_in[4];  // 10x768
    const float* bhx  = (const float*)d_in[5];  // 10
    float* out = (float*)d_out;                 // 40960 y_pred + 4 scalars
    char* ws = (char*)d_ws;
    unsigned short* keyT  = (unsigned short*)(ws + WS_KEYT);
    unsigned short* bimg  = (unsigned short*)(ws + WS_BIMG);
    float* conceptT       = (float*)(ws + WS_CONT);
    float* gram           = (float*)(ws + WS_GRAM);
    float* pscore         = (float*)(ws + WS_PSCORE);
    float* ct             = (float*)(ws + WS_CT);
    int* cand             = (int*)(ws + WS_CAND);
    float* psum           = (float*)(ws + WS_PSUM);
    float* tsol           = (float*)(ws + WS_TSOL);

    k_prep    <<<dim3(384), dim3(256), 0, stream>>>(cpt, conceptT, bimg);
    k_gram    <<<dim3(128), dim3(128), 0, stream>>>(cpt, gram);
    k_l2new   <<<dim3(1),   dim3(128), 0, stream>>>(gram, out + 40963);
    k_cg      <<<dim3(NCLS),dim3(128), 0, stream>>>(gram, cpt, whx, tsol);
    k_ct      <<<dim3(30),  dim3(256), 0, stream>>>(cpt, tsol, ct);
    k_ypred   <<<dim3(512), dim3(256), 0, stream>>>(te, ct, bhx, out);
    k_score   <<<dim3(1000),dim3(192), 0, stream>>>(clus, cpt, pscore);
    k_old     <<<dim3(1),   dim3(1024),0, stream>>>(pscore, gram, out + 40960);
    k_P       <<<dim3((M_TRAIN + 127) / 128), dim3(256), 0, stream>>>(tes, bimg, keyT);
    k_select  <<<dim3(128 * NCHUNK), dim3(256), 0, stream>>>(keyT, cand);
    k_refine  <<<dim3(128), dim3(512), 0, stream>>>(tes, conceptT, cand, psum);
    k_finalize<<<dim3(1),   dim3(128), 0, stream>>>(psum, out + 40962);
}

// Round 5
// 493.797 us; speedup vs baseline: 2.1013x; 1.0285x over previous
//
#include <hip/hip_runtime.h>
#include <stdint.h>

#define M_TRAIN 100000
#define D_DIM   768
#define C_DIM   128
#define NCLUST  500
#define CSIZE   100
#define NCLS    10
#define KSEL    10
#define NCHUNK  4
#define CHUNKN  25000
#define CAND_PER 16
#define NCT     (NCHUNK * CAND_PER)   // 64 candidates per concept
#define FLT_INF 3.402823466e38f

typedef __attribute__((ext_vector_type(8))) short bhalf8;
typedef __attribute__((ext_vector_type(4))) float f32x4;
typedef __attribute__((ext_vector_type(8))) unsigned short ushort8;
typedef __attribute__((ext_vector_type(4))) unsigned short ushort4v;

// ws layout (bytes)
#define WS_KEYT   0LL          // 128*100000*2 = 25,600,000 (bf16 keys)
#define WS_BIMG   25600000LL   // 768*128*2 = 196,608 (12 chunks x 16KB, pre-swizzled)
#define WS_CONT   25796608LL   // conceptT 128*768*4 = 393,216
#define WS_GRAM   26189824LL   // 128*128*4 = 65,536
#define WS_PSCORE 26255360LL   // 2*500*128*4 = 512,000
#define WS_CT     26767360LL   // 768*10*4 = 30,720
#define WS_CAND   26798080LL   // 128*64*4 = 32,768
#define WS_PSUM   26830848LL   // 128*4
#define WS_TSOL   26831360LL   // 128*10*4 = 5,120

static __device__ __forceinline__ unsigned short f2bf(float f) {
    union { float f; unsigned int u; } x; x.f = f;
    unsigned int u = x.u;
    return (unsigned short)((u + 0x7fffu + ((u >> 16) & 1u)) >> 16);
}

// ------- merged prep (conceptT + pre-swizzled bf16 B image) + gram -------
__global__ void __launch_bounds__(256) k_prepgram(const float* __restrict__ cpt,
        float* __restrict__ conceptT, unsigned short* __restrict__ bimg,
        float* __restrict__ gram) {
    int b = blockIdx.x, t = threadIdx.x;
    if (b < 384) {
        int tid = b * 256 + t;                 // 0..98303
        int d = tid >> 7, c = tid & 127;
        float v = cpt[tid];
        conceptT[c * D_DIM + d] = v;
        int kc = d >> 6, kin = d & 63;
        int ofs = kc * 16384 + (((c << 7) + (kin << 1)) ^ ((c & 7) << 4));
        *(unsigned short*)((char*)bimg + ofs) = f2bf(v);
    } else {
        int c1 = (b - 384) * 2 + (t >> 7);     // 64 blocks x 2 rows
        int c2 = t & 127;
        float s = 0.f;
        #pragma unroll 4
        for (int d = 0; d < D_DIM; ++d)
            s += cpt[d * 128 + c1] * cpt[d * 128 + c2];
        gram[c1 * 128 + c2] = s;
    }
}

// ------- CG solve (10 blocks, one per RHS) + folded L2new in block 0 -------
#define GSTR 132
__device__ __forceinline__ float blk_red(float v, float* buf, int t) {
    #pragma unroll
    for (int m = 32; m > 0; m >>= 1) v += __shfl_xor(v, m);
    if ((t & 63) == 0) buf[t >> 6] = v;
    __syncthreads();
    return buf[0] + buf[1];
}

__global__ void __launch_bounds__(128) k_cg(const float* __restrict__ gram,
        const float* __restrict__ cpt, const float* __restrict__ whx,
        float* __restrict__ tsol, float* __restrict__ out_l2new) {
    __shared__ float G[128 * GSTR];
    __shared__ float p_s[128];
    __shared__ float rbuf[4];
    int j = blockIdx.x, t = threadIdx.x;       // t = row r
    #pragma unroll 8
    for (int c = 0; c < 128; c += 4)
        *(float4*)&G[t * GSTR + c] = *(const float4*)&gram[t * 128 + c];
    const float* wj = whx + j * D_DIM;
    float rhs = 0.f;
    for (int d = 0; d < D_DIM; d += 4) {
        rhs += cpt[(d + 0) * 128 + t] * wj[d + 0]
             + cpt[(d + 1) * 128 + t] * wj[d + 1]
             + cpt[(d + 2) * 128 + t] * wj[d + 2]
             + cpt[(d + 3) * 128 + t] * wj[d + 3];
    }
    if (j == 0) {   // L2new from own G row (no barrier needed: own-row read)
        float s = 0.f;
        #pragma unroll 8
        for (int c = 0; c < 128; ++c) s += G[t * GSTR + c];
        s -= G[t * GSTR + t];
        float tot = blk_red(s, rbuf + 2, t);
        if (t == 0) out_l2new[0] = tot / 16384.0f;
    }
    float x = 0.f, res = rhs, p = rhs;
    p_s[t] = p;
    float rr = blk_red(res * res, rbuf, t);
    __syncthreads();   // G + p_s visible to all
    for (int it = 0; it < 20; ++it) {
        float q = 0.f;
        #pragma unroll 8
        for (int c = 0; c < 128; c += 4) {
            float4 g  = *(const float4*)&G[t * GSTR + c];
            float4 pp = *(const float4*)&p_s[c];     // broadcast
            q += g.x * pp.x + g.y * pp.y + g.z * pp.z + g.w * pp.w;
        }
        float pq = blk_red(p * q, rbuf + 2, t);
        float alpha = rr / pq;
        x += alpha * p;
        res -= alpha * q;
        float rrn = blk_red(res * res, rbuf, t);
        float beta = rrn / rr;
        rr = rrn;
        p = res + beta * p;
        p_s[t] = p;
        __syncthreads();
    }
    tsol[t * NCLS + j] = x;
}

// ------- ct[d][j] = sum_c cpt[d][c] * tsol[c][j] -------
__global__ void __launch_bounds__(256) k_ct(const float* __restrict__ cpt,
        const float* __restrict__ tsol, float* __restrict__ ct) {
    int idx = blockIdx.x * 256 + threadIdx.x;   // 0..7679
    int d = idx / NCLS, j = idx - d * NCLS;
    const float* crow = cpt + d * 128;
    float s = 0.f;
    #pragma unroll 4
    for (int c = 0; c < 128; ++c) s += crow[c] * tsol[c * NCLS + j];
    ct[idx] = s;
}

// ------- y_pred = X @ ct + b (4096x10) -------
__global__ void k_ypred(const float* __restrict__ te, const float* __restrict__ ct,
                        const float* __restrict__ bhx, float* __restrict__ out) {
    __shared__ float ctT[NCLS][D_DIM];
    int t = threadIdx.x;
    for (int o = t; o < D_DIM * NCLS; o += 256) {
        int j = o / D_DIM, d = o % D_DIM;
        ctT[j][d] = ct[d * NCLS + j];
    }
    __syncthreads();
    int r = t >> 5, l = t & 31;
    long row = (long)blockIdx.x * 8 + r;
    const float* er = te + row * D_DIM;
    float acc[NCLS];
    #pragma unroll
    for (int j = 0; j < NCLS; ++j) acc[j] = 0.f;
    for (int d0 = l * 4; d0 < D_DIM; d0 += 128) {
        float4 e = *(const float4*)(er + d0);
        #pragma unroll
        for (int j = 0; j < NCLS; ++j) {
            float4 cc = *(const float4*)(&ctT[j][d0]);
            acc[j] += e.x*cc.x + e.y*cc.y + e.z*cc.z + e.w*cc.w;
        }
    }
    #pragma unroll
    for (int j = 0; j < NCLS; ++j) {
        #pragma unroll
        for (int m = 16; m > 0; m >>= 1) acc[j] += __shfl_xor(acc[j], m);
    }
    if (l == 0) {
        #pragma unroll
        for (int j = 0; j < NCLS; ++j) out[row * NCLS + j] = acc[j] + bhx[j];
    }
}

// ------- partial cluster mean-dot: pscore[h][cl][c] -------
__global__ void __launch_bounds__(192) k_score(const float* __restrict__ clus,
        const float* __restrict__ cpt, float* __restrict__ pscore) {
    __shared__ float mean_s[D_DIM];
    int cl = blockIdx.x >> 1, h = blockIdx.x & 1;
    int t = threadIdx.x;
    const float* base = clus + (long)cl * CSIZE * D_DIM + (long)h * 50 * D_DIM + t * 4;
    float ax = 0.f, ay = 0.f, az = 0.f, aw = 0.f;
    for (int s = 0; s < 50; s += 2) {
        float4 v0 = *(const float4*)(base + (long)s * D_DIM);
        float4 v1 = *(const float4*)(base + (long)(s + 1) * D_DIM);
        ax += v0.x + v1.x; ay += v0.y + v1.y;
        az += v0.z + v1.z; aw += v0.w + v1.w;
    }
    const float k = 1.0f / CSIZE;
    mean_s[t * 4 + 0] = ax * k; mean_s[t * 4 + 1] = ay * k;
    mean_s[t * 4 + 2] = az * k; mean_s[t * 4 + 3] = aw * k;
    __syncthreads();
    if (t < 128) {
        float s = 0.f;
        #pragma unroll 4
        for (int d = 0; d < D_DIM; ++d) s += mean_s[d] * cpt[d * 128 + t];
        pscore[h * (NCLUST * 128) + cl * 128 + t] = s;
    }
}

// ------- L1old, L2old from pscore halves -------
__global__ void __launch_bounds__(1024) k_old(const float* __restrict__ pscore,
        const float* __restrict__ gram, float* __restrict__ out01) {
    __shared__ float ss8[8][128];
    __shared__ float sm8[8][128];
    __shared__ float rcn_s[128];
    __shared__ float wcomb[128];
    __shared__ float redA[128];
    __shared__ float redB[128];
    __shared__ float wred[16];
    __shared__ float trace_tot_s;
    const float* p0 = pscore;
    const float* p1 = pscore + NCLUST * 128;
    int t = threadIdx.x;
    if (t < 128) rcn_s[t] = 1.0f / fmaxf(sqrtf(gram[t * 129]), 1e-12f);
    __syncthreads();
    int c = t & 127, w8 = t >> 7;
    float rc = rcn_s[c];
    float ss = 0.f, sm = 0.f;
    for (int cl = w8; cl < NCLUST; cl += 8) {
        float v = fabsf(p0[cl * 128 + c] + p1[cl * 128 + c]) * rc;
        ss += v * v; sm += v;
    }
    ss8[w8][c] = ss; sm8[w8][c] = sm;
    __syncthreads();
    if (t < 128) {
        float S = 0.f, M = 0.f;
        #pragma unroll
        for (int i = 0; i < 8; ++i) { S += ss8[i][t]; M += sm8[i][t]; }
        float nn = fmaxf(sqrtf(S), 1e-12f);
        float iv = 1.0f / nn;
        wcomb[t] = rcn_s[t] * iv;
        redA[t] = M * iv;
        redB[t] = S * iv * iv;
    }
    __syncthreads();
    if (t < 64) {
        float a = redA[t] + redA[t + 64];
        float b = redB[t] + redB[t + 64];
        #pragma unroll
        for (int m = 32; m > 0; m >>= 1) { a += __shfl_xor(a, m); b += __shfl_xor(b, m); }
        if (t == 0) { out01[0] = a; trace_tot_s = b; }
    }
    __syncthreads();
    int w = t >> 6, lane = t & 63;
    float rsq = 0.f;
    for (int cl = w; cl < NCLUST; cl += 16) {
        float v = fabsf(p0[cl * 128 + lane] + p1[cl * 128 + lane]) * wcomb[lane]
                + fabsf(p0[cl * 128 + 64 + lane] + p1[cl * 128 + 64 + lane]) * wcomb[64 + lane];
        #pragma unroll
        for (int m = 32; m > 0; m >>= 1) v += __shfl_xor(v, m);
        if (lane == 0) rsq += v * v;
    }
    if (lane == 0) wred[w] = rsq;
    __syncthreads();
    if (t == 0) {
        float s = 0.f;
        for (int i = 0; i < 16; ++i) s += wred[i];
        out01[1] = s - trace_tot_s;
    }
}

// ------- big MFMA, pipelined: keyT[c][n] = bf16(e_sq[n] - 2*(E@C)[n][c]) -------
// Double-buffered LDS (one barrier per K-step), register prefetch of K-step
// k+1 issued before the MFMA block (HBM latency hides under MFMA+ds_read),
// coalesced epilogue via LDS C-stage (256B contiguous column segments).
__global__ void __launch_bounds__(256, 2) k_P(const float* __restrict__ E,
        const unsigned short* __restrict__ bimg, unsigned short* __restrict__ keyT) {
    __shared__ __align__(16) char lds[65536];   // A dbuf 0..32K, B dbuf 32K..64K
    __shared__ float esq_s[128];
    unsigned short* cst = (unsigned short*)lds; // epilogue overlay [128][136] ushorts

    int t = threadIdx.x;
    int rowbase = blockIdx.x * 128;
    int lane = t & 63, w = t >> 6;
    int wr = w >> 1, wc = w & 1;
    f32x4 acc[4][4];
    #pragma unroll
    for (int m = 0; m < 4; ++m)
        #pragma unroll
        for (int n = 0; n < 4; ++n) acc[m][n] = (f32x4){0.f, 0.f, 0.f, 0.f};
    float esq_p[4] = {0.f, 0.f, 0.f, 0.f};
    int g = t >> 3, k8 = t & 7;

    float4 a0[4], a1[4];   // prefetch regs
    bhalf8 breg[4];

    auto stage_issue = [&](int ks) {
        #pragma unroll
        for (int p = 0; p < 4; ++p) {
            int grow = rowbase + 32 * p + g;
            if (grow < M_TRAIN) {
                const float* src = E + (long)grow * D_DIM + ks * 64 + k8 * 8;
                a0[p] = *(const float4*)(src);
                a1[p] = *(const float4*)(src + 4);
            } else {
                a0[p] = make_float4(0.f, 0.f, 0.f, 0.f);
                a1[p] = make_float4(0.f, 0.f, 0.f, 0.f);
            }
        }
        const char* bs = (const char*)bimg + ks * 16384;
        #pragma unroll
        for (int i = 0; i < 4; ++i)
            breg[i] = *(const bhalf8*)(bs + (i * 256 + t) * 16);
    };
    auto stage_write = [&](int buf) {
        char* Ab = lds + buf * 16384;
        char* Bb = lds + 32768 + buf * 16384;
        #pragma unroll
        for (int p = 0; p < 4; ++p) {
            int row = 32 * p + g;
            float4 v0 = a0[p], v1 = a1[p];
            esq_p[p] += v0.x*v0.x + v0.y*v0.y + v0.z*v0.z + v0.w*v0.w
                      + v1.x*v1.x + v1.y*v1.y + v1.z*v1.z + v1.w*v1.w;
            bhalf8 h;
            h[0] = (short)f2bf(v0.x); h[1] = (short)f2bf(v0.y);
            h[2] = (short)f2bf(v0.z); h[3] = (short)f2bf(v0.w);
            h[4] = (short)f2bf(v1.x); h[5] = (short)f2bf(v1.y);
            h[6] = (short)f2bf(v1.z); h[7] = (short)f2bf(v1.w);
            int byte = (row * 128 + k8 * 16) ^ ((row & 7) << 4);
            *(bhalf8*)(Ab + byte) = h;
        }
        #pragma unroll
        for (int i = 0; i < 4; ++i)
            *(bhalf8*)(Bb + (i * 256 + t) * 16) = breg[i];
    };

    stage_issue(0);
    stage_write(0);
    __syncthreads();
    int cur = 0;
    for (int ks = 0; ks < 12; ++ks) {
        if (ks < 11) stage_issue(ks + 1);     // loads in flight across MFMA
        const char* Ab = lds + cur * 16384;
        const char* Bb = lds + 32768 + cur * 16384;
        bhalf8 af[4][2], bf[4][2];
        int kb = (lane >> 4) * 16;
        #pragma unroll
        for (int m = 0; m < 4; ++m) {
            int row = wr * 64 + m * 16 + (lane & 15);
            int b0 = row * 128, sw = (row & 7) << 4;
            af[m][0] = *(const bhalf8*)(Ab + ((b0 + kb) ^ sw));
            af[m][1] = *(const bhalf8*)(Ab + ((b0 + kb + 64) ^ sw));
        }
        #pragma unroll
        for (int n = 0; n < 4; ++n) {
            int c = wc * 64 + n * 16 + (lane & 15);
            int b0 = c * 128, sw = (c & 7) << 4;
            bf[n][0] = *(const bhalf8*)(Bb + ((b0 + kb) ^ sw));
            bf[n][1] = *(const bhalf8*)(Bb + ((b0 + kb + 64) ^ sw));
        }
        #pragma unroll
        for (int m = 0; m < 4; ++m)
            #pragma unroll
            for (int n = 0; n < 4; ++n) {
                acc[m][n] = __builtin_amdgcn_mfma_f32_16x16x32_bf16(af[m][0], bf[n][0], acc[m][n], 0, 0, 0);
                acc[m][n] = __builtin_amdgcn_mfma_f32_16x16x32_bf16(af[m][1], bf[n][1], acc[m][n], 0, 0, 0);
            }
        if (ks < 11) stage_write(cur ^ 1);    // write other buffer: no race with readers
        __syncthreads();                      // buf[cur^1] complete for next iter
        cur ^= 1;
    }
    #pragma unroll
    for (int p = 0; p < 4; ++p) {
        float v = esq_p[p];
        v += __shfl_xor(v, 1); v += __shfl_xor(v, 2); v += __shfl_xor(v, 4);
        if (k8 == 0) esq_s[32 * p + g] = v;
    }
    __syncthreads();
    // C-stage: cst[c][r] bf16, stride 136 ushorts
    #pragma unroll
    for (int m = 0; m < 4; ++m) {
        int r0 = wr * 64 + m * 16 + (lane >> 4) * 4;
        float e0 = esq_s[r0], e1 = esq_s[r0 + 1], e2 = esq_s[r0 + 2], e3 = esq_s[r0 + 3];
        #pragma unroll
        for (int n = 0; n < 4; ++n) {
            int c = wc * 64 + n * 16 + (lane & 15);
            ushort4v kv;
            kv[0] = f2bf(e0 - 2.f * acc[m][n][0]);
            kv[1] = f2bf(e1 - 2.f * acc[m][n][1]);
            kv[2] = f2bf(e2 - 2.f * acc[m][n][2]);
            kv[3] = f2bf(e3 - 2.f * acc[m][n][3]);
            *(ushort4v*)(cst + c * 136 + r0) = kv;
        }
    }
    __syncthreads();
    // coalesced store: per wave-instr 4 columns x 256B contiguous
    #pragma unroll
    for (int it = 0; it < 8; ++it) {
        int c = w * 32 + it * 4 + (lane >> 4);
        int r = (lane & 15) * 8;
        if (rowbase + r < M_TRAIN) {
            ushort8 v = *(const ushort8*)(cst + c * 136 + r);
            *(ushort8*)(keyT + (long)c * M_TRAIN + rowbase + r) = v;
        }
    }
}

// ------- per-(concept, quarter) approximate top-16 (bf16 keys, uint16 order) -------
__global__ void __launch_bounds__(256) k_select(const unsigned short* __restrict__ keyT,
                                                int* __restrict__ cand) {
    __shared__ int sk[2048];
    __shared__ int si[2048];
    __shared__ int wk[4]; __shared__ int wi[4], wsl[4];
    int c = blockIdx.x >> 2, h = blockIdx.x & 3;
    int t = threadIdx.x;
    const unsigned short* col = keyT + (long)c * M_TRAIN + h * CHUNKN;
    int base = h * CHUNKN;
    int tk[8], ti[8];
    #pragma unroll
    for (int i = 0; i < 8; ++i) { tk[i] = 0x7fffffff; ti[i] = 0x7fffffff; }
    for (int i = t; i < CHUNKN / 8; i += 256) {
        ushort8 v = *(const ushort8*)(col + i * 8);
        int idx = base + i * 8;
        #pragma unroll
        for (int q = 0; q < 8; ++q) {
            int cv = (int)v[q]; int ci = idx + q;
            if (cv < tk[7] || (cv == tk[7] && ci < ti[7])) {
                #pragma unroll
                for (int jj = 0; jj < 8; ++jj) {
                    bool sw = (cv < tk[jj]) || (cv == tk[jj] && ci < ti[jj]);
                    int ok = tk[jj]; int oi = ti[jj];
                    if (sw) { tk[jj] = cv; ti[jj] = ci; cv = ok; ci = oi; }
                }
            }
        }
    }
    #pragma unroll
    for (int i = 0; i < 8; ++i) { sk[t * 8 + i] = tk[i]; si[t * 8 + i] = ti[i]; }
    __syncthreads();
    int lane = t & 63, w = t >> 6;
    for (int sel = 0; sel < CAND_PER; ++sel) {
        int bk = 0x7fffffff, bi = 0x7fffffff, bs = -1;
        #pragma unroll
        for (int i = 0; i < 8; ++i) {
            int s = t * 8 + i;
            int v = sk[s];
            if (v < bk || (v == bk && si[s] < bi)) { bk = v; bi = si[s]; bs = s; }
        }
        #pragma unroll
        for (int m = 32; m > 0; m >>= 1) {
            int ok = __shfl_xor(bk, m); int oi = __shfl_xor(bi, m); int os = __shfl_xor(bs, m);
            if (ok < bk || (ok == bk && oi < bi)) { bk = ok; bi = oi; bs = os; }
        }
        if (lane == 0) { wk[w] = bk; wi[w] = bi; wsl[w] = bs; }
        __syncthreads();
        if (t == 0) {
            int fk = wk[0], fi = wi[0], fs = wsl[0];
            for (int i = 1; i < 4; ++i)
                if (wk[i] < fk || (wk[i] == fk && wi[i] < fi)) { fk = wk[i]; fi = wi[i]; fs = wsl[i]; }
            cand[(c * NCHUNK + h) * CAND_PER + sel] = fi;
            sk[fs] = 0x7fffffff; si[fs] = 0x7fffffff;
        }
        __syncthreads();
    }
}

// ------- exact f32 re-rank of 64 candidates, sum top-10 dots -------
__global__ void __launch_bounds__(512) k_refine(const float* __restrict__ E,
        const float* __restrict__ conceptT, const int* __restrict__ cand,
        float* __restrict__ psum) {
    __shared__ float skey[NCT], sdot[NCT];
    __shared__ int sidx[NCT];
    int c = blockIdx.x, t = threadIdx.x;
    int g = t >> 3, l8 = t & 7;
    int idx = cand[c * NCT + g];
    const float* er = E + (long)idx * D_DIM;
    const float* cr = conceptT + c * D_DIM;
    float dot = 0.f, ss = 0.f;
    for (int d0 = l8 * 4; d0 < D_DIM; d0 += 32) {
        float4 e = *(const float4*)(er + d0);
        float4 cc = *(const float4*)(cr + d0);
        dot += e.x*cc.x + e.y*cc.y + e.z*cc.z + e.w*cc.w;
        ss  += e.x*e.x + e.y*e.y + e.z*e.z + e.w*e.w;
    }
    dot += __shfl_xor(dot, 1); dot += __shfl_xor(dot, 2); dot += __shfl_xor(dot, 4);
    ss  += __shfl_xor(ss, 1);  ss  += __shfl_xor(ss, 2);  ss  += __shfl_xor(ss, 4);
    if (l8 == 0) { skey[g] = ss - 2.f * dot; sdot[g] = dot; sidx[g] = idx; }
    __syncthreads();
    if (t == 0) {
        float sum = 0.f;
        unsigned long long used = 0ull;
        for (int s = 0; s < KSEL; ++s) {
            float bk = FLT_INF; int bi = 0x7fffffff, bs = 0;
            for (int i = 0; i < NCT; ++i) {
                if ((used >> i) & 1ull) continue;
                if (skey[i] < bk || (skey[i] == bk && sidx[i] < bi)) { bk = skey[i]; bi = sidx[i]; bs = i; }
            }
            used |= (1ull << bs);
            sum += sdot[bs];
        }
        psum[c] = sum;
    }
}

__global__ void k_finalize(const float* __restrict__ psum, float* __restrict__ out2) {
    __shared__ float red[128];
    int t = threadIdx.x;
    red[t] = psum[t];
    __syncthreads();
    for (int s = 64; s > 0; s >>= 1) { if (t < s) red[t] += red[t + s]; __syncthreads(); }
    if (t == 0) out2[0] = red[0] * (1.0f / (C_DIM * KSEL));
}

extern "C" void kernel_launch(void* const* d_in, const int* in_sizes, int n_in,
                              void* d_out, int out_size, void* d_ws, size_t ws_size,
                              hipStream_t stream) {
    (void)in_sizes; (void)n_in; (void)out_size; (void)ws_size;
    const float* te   = (const float*)d_in[0];  // 4096x768
    const float* cpt  = (const float*)d_in[1];  // 768x128
    const float* clus = (const float*)d_in[2];  // 500x100x768
    const float* tes  = (const float*)d_in[3];  // 100000x768
    const float* whx  = (const float*)d_in[4];  // 10x768
    const float* bhx  = (const float*)d_in[5];  // 10
    float* out = (float*)d_out;                 // 40960 y_pred + 4 scalars
    char* ws = (char*)d_ws;
    unsigned short* keyT  = (unsigned short*)(ws + WS_KEYT);
    unsigned short* bimg  = (unsigned short*)(ws + WS_BIMG);
    float* conceptT       = (float*)(ws + WS_CONT);
    float* gram           = (float*)(ws + WS_GRAM);
    float* pscore         = (float*)(ws + WS_PSCORE);
    float* ct             = (float*)(ws + WS_CT);
    int* cand             = (int*)(ws + WS_CAND);
    float* psum           = (float*)(ws + WS_PSUM);
    float* tsol           = (float*)(ws + WS_TSOL);

    k_prepgram<<<dim3(448), dim3(256), 0, stream>>>(cpt, conceptT, bimg, gram);
    k_cg      <<<dim3(NCLS),dim3(128), 0, stream>>>(gram, cpt, whx, tsol, out + 40963);
    k_ct      <<<dim3(30),  dim3(256), 0, stream>>>(cpt, tsol, ct);
    k_ypred   <<<dim3(512), dim3(256), 0, stream>>>(te, ct, bhx, out);
    k_score   <<<dim3(1000),dim3(192), 0, stream>>>(clus, cpt, pscore);
    k_old     <<<dim3(1),   dim3(1024),0, stream>>>(pscore, gram, out + 40960);
    k_P       <<<dim3((M_TRAIN + 127) / 128), dim3(256), 0, stream>>>(tes, bimg, keyT);
    k_select  <<<dim3(128 * NCHUNK), dim3(256), 0, stream>>>(keyT, cand);
    k_refine  <<<dim3(128), dim3(512), 0, stream>>>(tes, conceptT, cand, psum);
    k_finalize<<<dim3(1),   dim3(128), 0, stream>>>(psum, out + 40962);
}

// Round 6
// 336.722 us; speedup vs baseline: 3.0815x; 1.4665x over previous
//
#include <hip/hip_runtime.h>
#include <stdint.h>

#define M_TRAIN 100000
#define D_DIM   768
#define C_DIM   128
#define NCLUST  500
#define CSIZE   100
#define NCLS    10
#define KSEL    10
#define NCHUNK  4
#define CHUNKN  25000
#define CAND_PER 16
#define NCT     (NCHUNK * CAND_PER)   // 64 candidates per concept
#define FLT_INF 3.402823466e38f

typedef __attribute__((ext_vector_type(8))) short bhalf8;
typedef __attribute__((ext_vector_type(4))) float f32x4;
typedef __attribute__((ext_vector_type(8))) unsigned short ushort8;
typedef __attribute__((ext_vector_type(4))) unsigned short ushort4v;

// ws layout (bytes)
#define WS_KEYT   0LL          // 128*100000*2 = 25,600,000 (bf16 keys)
#define WS_BIMG   25600000LL   // 768*128*2 = 196,608 (12 chunks x 16KB, pre-swizzled)
#define WS_CONT   25796608LL   // conceptT 128*768*4 = 393,216
#define WS_GRAM   26189824LL   // 128*128*4
#define WS_PSCORE 26255360LL   // 2*500*128*4
#define WS_CT     26767360LL   // 768*10*4
#define WS_CAND   26798080LL   // 128*64*4
#define WS_PSUM   26830848LL   // 128*4
#define WS_TSOL   26831360LL   // 128*10*4

#define GSTR 132

static __device__ __forceinline__ unsigned short f2bf(float f) {
    union { float f; unsigned int u; } x; x.f = f;
    unsigned int u = x.u;
    return (unsigned short)((u + 0x7fffu + ((u >> 16) & 1u)) >> 16);
}

// ======================= kA: score(1000) | prep(384) | gram(64) =======================
__global__ void __launch_bounds__(256) kA(const float* __restrict__ cpt,
        const float* __restrict__ clus, float* __restrict__ conceptT,
        unsigned short* __restrict__ bimg, float* __restrict__ gram,
        float* __restrict__ pscore) {
    int b = blockIdx.x, t = threadIdx.x;
    if (b < 1000) {          // ---- score: partial cluster mean-dot ----
        __shared__ float mean_s[D_DIM];
        int cl = b >> 1, h = b & 1;
        if (t < 192) {
            const float* base = clus + (long)cl * CSIZE * D_DIM + (long)h * 50 * D_DIM + t * 4;
            float ax = 0.f, ay = 0.f, az = 0.f, aw = 0.f;
            for (int s = 0; s < 50; s += 2) {
                float4 v0 = *(const float4*)(base + (long)s * D_DIM);
                float4 v1 = *(const float4*)(base + (long)(s + 1) * D_DIM);
                ax += v0.x + v1.x; ay += v0.y + v1.y;
                az += v0.z + v1.z; aw += v0.w + v1.w;
            }
            const float k = 1.0f / CSIZE;
            mean_s[t * 4 + 0] = ax * k; mean_s[t * 4 + 1] = ay * k;
            mean_s[t * 4 + 2] = az * k; mean_s[t * 4 + 3] = aw * k;
        }
        __syncthreads();
        if (t < 128) {
            float s = 0.f;
            #pragma unroll 4
            for (int d = 0; d < D_DIM; ++d) s += mean_s[d] * cpt[d * 128 + t];
            pscore[h * (NCLUST * 128) + cl * 128 + t] = s;
        }
    } else if (b < 1384) {   // ---- prep: conceptT + pre-swizzled bf16 B image ----
        int tid = (b - 1000) * 256 + t;        // 0..98303
        int d = tid >> 7, c = tid & 127;
        float v = cpt[tid];
        conceptT[c * D_DIM + d] = v;
        int kc = d >> 6, kin = d & 63;
        int ofs = kc * 16384 + (((c << 7) + (kin << 1)) ^ ((c & 7) << 4));
        *(unsigned short*)((char*)bimg + ofs) = f2bf(v);
    } else {                 // ---- gram ----
        int c1 = (b - 1384) * 2 + (t >> 7);
        int c2 = t & 127;
        float s = 0.f;
        #pragma unroll 4
        for (int d = 0; d < D_DIM; ++d)
            s += cpt[d * 128 + c1] * cpt[d * 128 + c2];
        gram[c1 * 128 + c2] = s;
    }
}

// ======================= kB roles: cg(10) + old(1) + P(782) =======================
__device__ __forceinline__ float blk_red256(float v, float* buf, int t) {
    #pragma unroll
    for (int m = 32; m > 0; m >>= 1) v += __shfl_xor(v, m);
    if ((t & 63) == 0) buf[t >> 6] = v;
    __syncthreads();
    return buf[0] + buf[1] + buf[2] + buf[3];
}

__device__ __forceinline__ void cg_role(char* smem, const float* __restrict__ gram,
        const float* __restrict__ cpt, const float* __restrict__ whx,
        float* __restrict__ tsol, float* __restrict__ out_l2new, int j) {
    float* G    = (float*)smem;               // 128*GSTR
    float* p_s  = (float*)(smem + 67584);     // 128
    float* rbuf = (float*)(smem + 68096);     // 12
    int t = threadIdx.x;
    int r = t & 127;
    bool lo = (t < 128);
    if (lo) {
        #pragma unroll 8
        for (int c = 0; c < 128; c += 4)
            *(float4*)&G[r * GSTR + c] = *(const float4*)&gram[r * 128 + c];
    }
    const float* wj = whx + j * D_DIM;
    float rhs = 0.f;
    if (lo) {
        for (int d = 0; d < D_DIM; d += 4)
            rhs += cpt[(d + 0) * 128 + r] * wj[d + 0]
                 + cpt[(d + 1) * 128 + r] * wj[d + 1]
                 + cpt[(d + 2) * 128 + r] * wj[d + 2]
                 + cpt[(d + 3) * 128 + r] * wj[d + 3];
    }
    float x = 0.f, res = rhs, p = rhs;
    if (lo) p_s[r] = p;
    float rr = blk_red256(lo ? res * res : 0.f, rbuf, t);
    __syncthreads();   // G + p_s visible
    if (j == 0) {      // L2new folded here (own slot rbuf+8)
        float s = 0.f;
        if (lo) {
            #pragma unroll 8
            for (int c = 0; c < 128; ++c) s += G[r * GSTR + c];
            s -= G[r * GSTR + r];
        }
        float tot = blk_red256(s, rbuf + 8, t);
        if (t == 0) out_l2new[0] = tot / 16384.0f;
    }
    for (int it = 0; it < 20; ++it) {
        float q = 0.f;
        if (lo) {
            #pragma unroll 8
            for (int c = 0; c < 128; c += 4) {
                float4 g  = *(const float4*)&G[r * GSTR + c];
                float4 pp = *(const float4*)&p_s[c];
                q += g.x * pp.x + g.y * pp.y + g.z * pp.z + g.w * pp.w;
            }
        }
        float pq = blk_red256(lo ? p * q : 0.f, rbuf + 4, t);
        float alpha = rr / pq;
        x += alpha * p;
        res -= alpha * q;
        float rrn = blk_red256(lo ? res * res : 0.f, rbuf, t);
        float beta = rrn / rr;
        rr = rrn;
        p = res + beta * p;
        if (lo) p_s[r] = p;
        __syncthreads();
    }
    if (lo) tsol[r * NCLS + j] = x;
}

__device__ __forceinline__ void old_role(char* smem, const float* __restrict__ pscore,
        const float* __restrict__ gram, float* __restrict__ out01) {
    float* ss2     = (float*)smem;             // 256
    float* sm2     = (float*)(smem + 1024);    // 256
    float* rcn_s   = (float*)(smem + 2048);    // 128
    float* wcomb   = (float*)(smem + 2560);    // 128
    float* redA    = (float*)(smem + 3072);    // 128
    float* redB    = (float*)(smem + 3584);    // 128
    float* wred4   = (float*)(smem + 4096);    // 4
    float* trace_s = (float*)(smem + 4112);    // 1
    const float* p0 = pscore;
    const float* p1 = pscore + NCLUST * 128;
    int t = threadIdx.x;
    int c = t & 127, w2 = t >> 7;
    if (t < 128) rcn_s[t] = 1.0f / fmaxf(sqrtf(gram[t * 129]), 1e-12f);
    __syncthreads();
    float rc = rcn_s[c];
    float ss = 0.f, sm = 0.f;
    for (int bb = 0; bb < 25; ++bb) {          // 10-deep load batches (ILP)
        float a[10];
        #pragma unroll
        for (int k = 0; k < 10; ++k) {
            int cl = w2 + 2 * (10 * bb + k);
            a[k] = p0[cl * 128 + c] + p1[cl * 128 + c];
        }
        #pragma unroll
        for (int k = 0; k < 10; ++k) { float v = fabsf(a[k]) * rc; ss += v * v; sm += v; }
    }
    ss2[w2 * 128 + c] = ss; sm2[w2 * 128 + c] = sm;
    __syncthreads();
    if (t < 128) {
        float S = ss2[t] + ss2[128 + t];
        float M = sm2[t] + sm2[128 + t];
        float nn = fmaxf(sqrtf(S), 1e-12f);
        float iv = 1.0f / nn;
        wcomb[t] = rcn_s[t] * iv;
        redA[t] = M * iv;
        redB[t] = S * iv * iv;
    }
    __syncthreads();
    if (t < 64) {
        float a = redA[t] + redA[t + 64];
        float b2 = redB[t] + redB[t + 64];
        #pragma unroll
        for (int m = 32; m > 0; m >>= 1) { a += __shfl_xor(a, m); b2 += __shfl_xor(b2, m); }
        if (t == 0) { out01[0] = a; trace_s[0] = b2; }
    }
    __syncthreads();
    int w = t >> 6, lane = t & 63;
    float wc0 = wcomb[lane], wc1 = wcomb[lane + 64];
    float rsq = 0.f;
    for (int bb = 0; bb < 25; ++bb) {          // 5-deep cluster batches per wave
        float a0[5], a1[5];
        #pragma unroll
        for (int k = 0; k < 5; ++k) {
            int cl = w + 4 * (5 * bb + k);
            a0[k] = p0[cl * 128 + lane] + p1[cl * 128 + lane];
            a1[k] = p0[cl * 128 + 64 + lane] + p1[cl * 128 + 64 + lane];
        }
        #pragma unroll
        for (int k = 0; k < 5; ++k) {
            float v = fabsf(a0[k]) * wc0 + fabsf(a1[k]) * wc1;
            #pragma unroll
            for (int m = 32; m > 0; m >>= 1) v += __shfl_xor(v, m);
            if (lane == 0) rsq += v * v;
        }
    }
    if (lane == 0) wred4[w] = rsq;
    __syncthreads();
    if (t == 0) out01[1] = wred4[0] + wred4[1] + wred4[2] + wred4[3] - trace_s[0];
}

__device__ __forceinline__ void P_role(char* smem, const float* __restrict__ E,
        const unsigned short* __restrict__ bimg, unsigned short* __restrict__ keyT,
        int blk) {
    char* lds = smem;                           // A dbuf 0..32K, B dbuf 32K..64K
    float* esq_s = (float*)(smem + 65536);      // 128
    unsigned short* cst = (unsigned short*)lds; // epilogue overlay [128][136]

    int t = threadIdx.x;
    int rowbase = blk * 128;
    int lane = t & 63, w = t >> 6;
    int wr = w >> 1, wc = w & 1;
    f32x4 acc[4][4];
    #pragma unroll
    for (int m = 0; m < 4; ++m)
        #pragma unroll
        for (int n = 0; n < 4; ++n) acc[m][n] = (f32x4){0.f, 0.f, 0.f, 0.f};
    float esq_p[4] = {0.f, 0.f, 0.f, 0.f};
    int g = t >> 3, k8 = t & 7;

    float4 a0[4], a1[4];
    bhalf8 breg[4];

    auto stage_issue = [&](int ks) {
        #pragma unroll
        for (int p = 0; p < 4; ++p) {
            int grow = rowbase + 32 * p + g;
            if (grow < M_TRAIN) {
                const float* src = E + (long)grow * D_DIM + ks * 64 + k8 * 8;
                a0[p] = *(const float4*)(src);
                a1[p] = *(const float4*)(src + 4);
            } else {
                a0[p] = make_float4(0.f, 0.f, 0.f, 0.f);
                a1[p] = make_float4(0.f, 0.f, 0.f, 0.f);
            }
        }
        const char* bs = (const char*)bimg + ks * 16384;
        #pragma unroll
        for (int i = 0; i < 4; ++i)
            breg[i] = *(const bhalf8*)(bs + (i * 256 + t) * 16);
    };
    auto stage_write = [&](int buf) {
        char* Ab = lds + buf * 16384;
        char* Bb = lds + 32768 + buf * 16384;
        #pragma unroll
        for (int p = 0; p < 4; ++p) {
            int row = 32 * p + g;
            float4 v0 = a0[p], v1 = a1[p];
            esq_p[p] += v0.x*v0.x + v0.y*v0.y + v0.z*v0.z + v0.w*v0.w
                      + v1.x*v1.x + v1.y*v1.y + v1.z*v1.z + v1.w*v1.w;
            bhalf8 h;
            h[0] = (short)f2bf(v0.x); h[1] = (short)f2bf(v0.y);
            h[2] = (short)f2bf(v0.z); h[3] = (short)f2bf(v0.w);
            h[4] = (short)f2bf(v1.x); h[5] = (short)f2bf(v1.y);
            h[6] = (short)f2bf(v1.z); h[7] = (short)f2bf(v1.w);
            int byte = (row * 128 + k8 * 16) ^ ((row & 7) << 4);
            *(bhalf8*)(Ab + byte) = h;
        }
        #pragma unroll
        for (int i = 0; i < 4; ++i)
            *(bhalf8*)(Bb + (i * 256 + t) * 16) = breg[i];
    };

    stage_issue(0);
    stage_write(0);
    __syncthreads();
    int cur = 0;
    for (int ks = 0; ks < 12; ++ks) {
        if (ks < 11) stage_issue(ks + 1);
        const char* Ab = lds + cur * 16384;
        const char* Bb = lds + 32768 + cur * 16384;
        bhalf8 af[4][2], bf[4][2];
        int kb = (lane >> 4) * 16;
        #pragma unroll
        for (int m = 0; m < 4; ++m) {
            int row = wr * 64 + m * 16 + (lane & 15);
            int b0 = row * 128, sw = (row & 7) << 4;
            af[m][0] = *(const bhalf8*)(Ab + ((b0 + kb) ^ sw));
            af[m][1] = *(const bhalf8*)(Ab + ((b0 + kb + 64) ^ sw));
        }
        #pragma unroll
        for (int n = 0; n < 4; ++n) {
            int c = wc * 64 + n * 16 + (lane & 15);
            int b0 = c * 128, sw = (c & 7) << 4;
            bf[n][0] = *(const bhalf8*)(Bb + ((b0 + kb) ^ sw));
            bf[n][1] = *(const bhalf8*)(Bb + ((b0 + kb + 64) ^ sw));
        }
        #pragma unroll
        for (int m = 0; m < 4; ++m)
            #pragma unroll
            for (int n = 0; n < 4; ++n) {
                acc[m][n] = __builtin_amdgcn_mfma_f32_16x16x32_bf16(af[m][0], bf[n][0], acc[m][n], 0, 0, 0);
                acc[m][n] = __builtin_amdgcn_mfma_f32_16x16x32_bf16(af[m][1], bf[n][1], acc[m][n], 0, 0, 0);
            }
        if (ks < 11) stage_write(cur ^ 1);
        __syncthreads();
        cur ^= 1;
    }
    #pragma unroll
    for (int p = 0; p < 4; ++p) {
        float v = esq_p[p];
        v += __shfl_xor(v, 1); v += __shfl_xor(v, 2); v += __shfl_xor(v, 4);
        if (k8 == 0) esq_s[32 * p + g] = v;
    }
    __syncthreads();
    #pragma unroll
    for (int m = 0; m < 4; ++m) {
        int r0 = wr * 64 + m * 16 + (lane >> 4) * 4;
        float e0 = esq_s[r0], e1 = esq_s[r0 + 1], e2 = esq_s[r0 + 2], e3 = esq_s[r0 + 3];
        #pragma unroll
        for (int n = 0; n < 4; ++n) {
            int c = wc * 64 + n * 16 + (lane & 15);
            ushort4v kv;
            kv[0] = f2bf(e0 - 2.f * acc[m][n][0]);
            kv[1] = f2bf(e1 - 2.f * acc[m][n][1]);
            kv[2] = f2bf(e2 - 2.f * acc[m][n][2]);
            kv[3] = f2bf(e3 - 2.f * acc[m][n][3]);
            *(ushort4v*)(cst + c * 136 + r0) = kv;
        }
    }
    __syncthreads();
    #pragma unroll
    for (int it = 0; it < 8; ++it) {
        int c = w * 32 + it * 4 + (lane >> 4);
        int r = (lane & 15) * 8;
        if (rowbase + r < M_TRAIN) {
            ushort8 v = *(const ushort8*)(cst + c * 136 + r);
            *(ushort8*)(keyT + (long)c * M_TRAIN + rowbase + r) = v;
        }
    }
}

__global__ void __launch_bounds__(256, 2) kB(const float* __restrict__ E,
        const unsigned short* __restrict__ bimg, unsigned short* __restrict__ keyT,
        const float* __restrict__ gram, const float* __restrict__ cpt,
        const float* __restrict__ whx, float* __restrict__ tsol,
        float* __restrict__ out_scal, const float* __restrict__ pscore) {
    __shared__ __align__(16) char smem[68160];
    int b = blockIdx.x;
    if (b < 10)       cg_role(smem, gram, cpt, whx, tsol, out_scal + 3, b);
    else if (b == 10) old_role(smem, pscore, gram, out_scal);
    else              P_role(smem, E, bimg, keyT, b - 11);
}

// ======================= kC: select(512) | ct(30) =======================
__global__ void __launch_bounds__(256) kC(const unsigned short* __restrict__ keyT,
        int* __restrict__ cand, const float* __restrict__ cpt,
        const float* __restrict__ tsol, float* __restrict__ ct) {
    int b = blockIdx.x, t = threadIdx.x;
    if (b < 512) {     // ---- select: per-(concept, quarter) top-16 ----
        __shared__ int sk[2048];
        __shared__ int si[2048];
        __shared__ int wk[4]; __shared__ int wi[4], wsl[4];
        int c = b >> 2, h = b & 3;
        const unsigned short* col = keyT + (long)c * M_TRAIN + h * CHUNKN;
        int base = h * CHUNKN;
        int tk[8], ti[8];
        #pragma unroll
        for (int i = 0; i < 8; ++i) { tk[i] = 0x7fffffff; ti[i] = 0x7fffffff; }
        for (int i = t; i < CHUNKN / 8; i += 256) {
            ushort8 v = *(const ushort8*)(col + i * 8);
            int idx = base + i * 8;
            #pragma unroll
            for (int q = 0; q < 8; ++q) {
                int cv = (int)v[q]; int ci = idx + q;
                if (cv < tk[7] || (cv == tk[7] && ci < ti[7])) {
                    #pragma unroll
                    for (int jj = 0; jj < 8; ++jj) {
                        bool sw = (cv < tk[jj]) || (cv == tk[jj] && ci < ti[jj]);
                        int ok = tk[jj]; int oi = ti[jj];
                        if (sw) { tk[jj] = cv; ti[jj] = ci; cv = ok; ci = oi; }
                    }
                }
            }
        }
        #pragma unroll
        for (int i = 0; i < 8; ++i) { sk[t * 8 + i] = tk[i]; si[t * 8 + i] = ti[i]; }
        __syncthreads();
        int lane = t & 63, w = t >> 6;
        for (int sel = 0; sel < CAND_PER; ++sel) {
            int bk = 0x7fffffff, bi = 0x7fffffff, bs = -1;
            #pragma unroll
            for (int i = 0; i < 8; ++i) {
                int s = t * 8 + i;
                int v = sk[s];
                if (v < bk || (v == bk && si[s] < bi)) { bk = v; bi = si[s]; bs = s; }
            }
            #pragma unroll
            for (int m = 32; m > 0; m >>= 1) {
                int ok = __shfl_xor(bk, m); int oi = __shfl_xor(bi, m); int os = __shfl_xor(bs, m);
                if (ok < bk || (ok == bk && oi < bi)) { bk = ok; bi = oi; bs = os; }
            }
            if (lane == 0) { wk[w] = bk; wi[w] = bi; wsl[w] = bs; }
            __syncthreads();
            if (t == 0) {
                int fk = wk[0], fi = wi[0], fs = wsl[0];
                for (int i = 1; i < 4; ++i)
                    if (wk[i] < fk || (wk[i] == fk && wi[i] < fi)) { fk = wk[i]; fi = wi[i]; fs = wsl[i]; }
                cand[(c * NCHUNK + h) * CAND_PER + sel] = fi;
                sk[fs] = 0x7fffffff; si[fs] = 0x7fffffff;
            }
            __syncthreads();
        }
    } else {           // ---- ct ----
        int idx = (b - 512) * 256 + t;     // 0..7679
        int d = idx / NCLS, j = idx - d * NCLS;
        const float* crow = cpt + d * 128;
        float s = 0.f;
        #pragma unroll 4
        for (int c = 0; c < 128; ++c) s += crow[c] * tsol[c * NCLS + j];
        ct[idx] = s;
    }
}

// ======================= kD: ypred(512) | refine(128) =======================
__global__ void __launch_bounds__(256) kD(const float* __restrict__ te,
        const float* __restrict__ ct, const float* __restrict__ bhx,
        float* __restrict__ out, const float* __restrict__ E,
        const float* __restrict__ conceptT, const int* __restrict__ cand,
        float* __restrict__ psum) {
    int b = blockIdx.x, t = threadIdx.x;
    if (b < 512) {     // ---- ypred ----
        __shared__ float ctT[NCLS][D_DIM];
        for (int o = t; o < D_DIM * NCLS; o += 256) {
            int j = o / D_DIM, d = o % D_DIM;
            ctT[j][d] = ct[d * NCLS + j];
        }
        __syncthreads();
        int r = t >> 5, l = t & 31;
        long row = (long)b * 8 + r;
        const float* er = te + row * D_DIM;
        float acc[NCLS];
        #pragma unroll
        for (int j = 0; j < NCLS; ++j) acc[j] = 0.f;
        for (int d0 = l * 4; d0 < D_DIM; d0 += 128) {
            float4 e = *(const float4*)(er + d0);
            #pragma unroll
            for (int j = 0; j < NCLS; ++j) {
                float4 cc = *(const float4*)(&ctT[j][d0]);
                acc[j] += e.x*cc.x + e.y*cc.y + e.z*cc.z + e.w*cc.w;
            }
        }
        #pragma unroll
        for (int j = 0; j < NCLS; ++j) {
            #pragma unroll
            for (int m = 16; m > 0; m >>= 1) acc[j] += __shfl_xor(acc[j], m);
        }
        if (l == 0) {
            #pragma unroll
            for (int j = 0; j < NCLS; ++j) out[row * NCLS + j] = acc[j] + bhx[j];
        }
    } else {           // ---- refine: exact f32 re-rank, 4 lanes/candidate ----
        __shared__ float skey[NCT], sdot[NCT];
        __shared__ int sidx[NCT];
        int c = b - 512;
        int g = t >> 2, l4 = t & 3;
        int idx = cand[c * NCT + g];
        const float* er = E + (long)idx * D_DIM;
        const float* cr = conceptT + c * D_DIM;
        float dot = 0.f, ss = 0.f;
        for (int d0 = l4 * 4; d0 < D_DIM; d0 += 16) {
            float4 e = *(const float4*)(er + d0);
            float4 cc = *(const float4*)(cr + d0);
            dot += e.x*cc.x + e.y*cc.y + e.z*cc.z + e.w*cc.w;
            ss  += e.x*e.x + e.y*e.y + e.z*e.z + e.w*e.w;
        }
        dot += __shfl_xor(dot, 1); dot += __shfl_xor(dot, 2);
        ss  += __shfl_xor(ss, 1);  ss  += __shfl_xor(ss, 2);
        if (l4 == 0) { skey[g] = ss - 2.f * dot; sdot[g] = dot; sidx[g] = idx; }
        __syncthreads();
        if (t == 0) {
            float sum = 0.f;
            unsigned long long used = 0ull;
            for (int s = 0; s < KSEL; ++s) {
                float bk = FLT_INF; int bi = 0x7fffffff, bs = 0;
                for (int i = 0; i < NCT; ++i) {
                    if ((used >> i) & 1ull) continue;
                    if (skey[i] < bk || (skey[i] == bk && sidx[i] < bi)) { bk = skey[i]; bi = sidx[i]; bs = i; }
                }
                used |= (1ull << bs);
                sum += sdot[bs];
            }
            psum[c] = sum;
        }
    }
}

__global__ void k_finalize(const float* __restrict__ psum, float* __restrict__ out2) {
    __shared__ float red[128];
    int t = threadIdx.x;
    red[t] = psum[t];
    __syncthreads();
    for (int s = 64; s > 0; s >>= 1) { if (t < s) red[t] += red[t + s]; __syncthreads(); }
    if (t == 0) out2[0] = red[0] * (1.0f / (C_DIM * KSEL));
}

extern "C" void kernel_launch(void* const* d_in, const int* in_sizes, int n_in,
                              void* d_out, int out_size, void* d_ws, size_t ws_size,
                              hipStream_t stream) {
    (void)in_sizes; (void)n_in; (void)out_size; (void)ws_size;
    const float* te   = (const float*)d_in[0];  // 4096x768
    const float* cpt  = (const float*)d_in[1];  // 768x128
    const float* clus = (const float*)d_in[2];  // 500x100x768
    const float* tes  = (const float*)d_in[3];  // 100000x768
    const float* whx  = (const float*)d_in[4];  // 10x768
    const float* bhx  = (const float*)d_in[5];  // 10
    float* out = (float*)d_out;                 // 40960 y_pred + 4 scalars
    char* ws = (char*)d_ws;
    unsigned short* keyT  = (unsigned short*)(ws + WS_KEYT);
    unsigned short* bimg  = (unsigned short*)(ws + WS_BIMG);
    float* conceptT       = (float*)(ws + WS_CONT);
    float* gram           = (float*)(ws + WS_GRAM);
    float* pscore         = (float*)(ws + WS_PSCORE);
    float* ct             = (float*)(ws + WS_CT);
    int* cand             = (int*)(ws + WS_CAND);
    float* psum           = (float*)(ws + WS_PSUM);
    float* tsol           = (float*)(ws + WS_TSOL);

    kA<<<dim3(1448), dim3(256), 0, stream>>>(cpt, clus, conceptT, bimg, gram, pscore);
    kB<<<dim3(793),  dim3(256), 0, stream>>>(tes, bimg, keyT, gram, cpt, whx, tsol,
                                             out + 40960, pscore);
    kC<<<dim3(542),  dim3(256), 0, stream>>>(keyT, cand, cpt, tsol, ct);
    kD<<<dim3(640),  dim3(256), 0, stream>>>(te, ct, bhx, out, tes, conceptT, cand, psum);
    k_finalize<<<dim3(1), dim3(128), 0, stream>>>(psum, out + 40962);
}

// Round 7
// 335.419 us; speedup vs baseline: 3.0935x; 1.0039x over previous
//
#include <hip/hip_runtime.h>
#include <hip/hip_bf16.h>
#include <stdint.h>

#define M_TRAIN 100000
#define D_DIM   768
#define C_DIM   128
#define NCLUST  500
#define CSIZE   100
#define NCLS    10
#define KSEL    10
#define NCHUNK  4
#define CHUNKN  25000
#define CAND_PER 16
#define NCT     (NCHUNK * CAND_PER)   // 64 candidates per concept
#define FLT_INF 3.402823466e38f

typedef __attribute__((ext_vector_type(8))) short bhalf8;
typedef __attribute__((ext_vector_type(4))) float f32x4;
typedef __attribute__((ext_vector_type(8))) unsigned short ushort8;
typedef __attribute__((ext_vector_type(4))) unsigned short ushort4v;

// ws layout (bytes)
#define WS_KEYT   0LL          // 128*100000*2 = 25,600,000 (bf16 keys)
#define WS_BIMG   25600000LL   // 768*128*2 = 196,608 (12 chunks x 16KB, pre-swizzled)
#define WS_CONT   25796608LL   // conceptT 128*768*4 = 393,216
#define WS_GRAM   26189824LL   // 128*128*4
#define WS_PSCORE 26255360LL   // 2*500*128*4
#define WS_CT     26767360LL   // 768*10*4
#define WS_CAND   26798080LL   // 128*64*4
#define WS_PSUM   26830848LL   // 128*4
#define WS_TSOL   26831360LL   // 128*10*4

#define GSTR 132

static __device__ __forceinline__ unsigned short f2bf(float f) {
    union { float f; unsigned int u; } x; x.f = f;
    unsigned int u = x.u;
    return (unsigned short)((u + 0x7fffu + ((u >> 16) & 1u)) >> 16);
}
// HW packed convert (v_cvt_pk_bf16_f32), RTNE — bit-identical to f2bf for finite vals
static __device__ __forceinline__ unsigned int f2bf2(float lo, float hi) {
    union { __hip_bfloat162 h; unsigned int u; } cv;
    cv.h = __float22bfloat162_rn(make_float2(lo, hi));
    return cv.u;
}

// ======================= kA: score(1000) | prep(384) | gram(64) =======================
__global__ void __launch_bounds__(256) kA(const float* __restrict__ cpt,
        const float* __restrict__ clus, float* __restrict__ conceptT,
        unsigned short* __restrict__ bimg, float* __restrict__ gram,
        float* __restrict__ pscore) {
    int b = blockIdx.x, t = threadIdx.x;
    if (b < 1000) {          // ---- score: partial cluster mean-dot ----
        __shared__ float mean_s[D_DIM];
        int cl = b >> 1, h = b & 1;
        if (t < 192) {
            const float* base = clus + (long)cl * CSIZE * D_DIM + (long)h * 50 * D_DIM + t * 4;
            float ax = 0.f, ay = 0.f, az = 0.f, aw = 0.f;
            for (int s = 0; s < 50; s += 2) {
                float4 v0 = *(const float4*)(base + (long)s * D_DIM);
                float4 v1 = *(const float4*)(base + (long)(s + 1) * D_DIM);
                ax += v0.x + v1.x; ay += v0.y + v1.y;
                az += v0.z + v1.z; aw += v0.w + v1.w;
            }
            const float k = 1.0f / CSIZE;
            mean_s[t * 4 + 0] = ax * k; mean_s[t * 4 + 1] = ay * k;
            mean_s[t * 4 + 2] = az * k; mean_s[t * 4 + 3] = aw * k;
        }
        __syncthreads();
        if (t < 128) {
            float s = 0.f;
            #pragma unroll 4
            for (int d = 0; d < D_DIM; ++d) s += mean_s[d] * cpt[d * 128 + t];
            pscore[h * (NCLUST * 128) + cl * 128 + t] = s;
        }
    } else if (b < 1384) {   // ---- prep: conceptT + pre-swizzled bf16 B image ----
        int tid = (b - 1000) * 256 + t;        // 0..98303
        int d = tid >> 7, c = tid & 127;
        float v = cpt[tid];
        conceptT[c * D_DIM + d] = v;
        int kc = d >> 6, kin = d & 63;
        int ofs = kc * 16384 + (((c << 7) + (kin << 1)) ^ ((c & 7) << 4));
        *(unsigned short*)((char*)bimg + ofs) = f2bf(v);
    } else {                 // ---- gram ----
        int c1 = (b - 1384) * 2 + (t >> 7);
        int c2 = t & 127;
        float s = 0.f;
        #pragma unroll 4
        for (int d = 0; d < D_DIM; ++d)
            s += cpt[d * 128 + c1] * cpt[d * 128 + c2];
        gram[c1 * 128 + c2] = s;
    }
}

// ======================= kB roles: cg(10)+ct + old(1) + P(782) =======================
__device__ __forceinline__ float blk_red256(float v, float* buf, int t) {
    #pragma unroll
    for (int m = 32; m > 0; m >>= 1) v += __shfl_xor(v, m);
    if ((t & 63) == 0) buf[t >> 6] = v;
    __syncthreads();
    return buf[0] + buf[1] + buf[2] + buf[3];
}

__device__ __forceinline__ void cg_role(char* smem, const float* __restrict__ gram,
        const float* __restrict__ cpt, const float* __restrict__ whx,
        float* __restrict__ tsol, float* __restrict__ ct,
        float* __restrict__ out_l2new, int j) {
    float* G    = (float*)smem;               // 128*GSTR
    float* p_s  = (float*)(smem + 67584);     // 128
    float* rbuf = (float*)(smem + 68096);     // 12
    int t = threadIdx.x;
    int r = t & 127;
    bool lo = (t < 128);
    if (lo) {
        #pragma unroll 8
        for (int c = 0; c < 128; c += 4)
            *(float4*)&G[r * GSTR + c] = *(const float4*)&gram[r * 128 + c];
    }
    const float* wj = whx + j * D_DIM;
    float rhs = 0.f;
    if (lo) {
        for (int d = 0; d < D_DIM; d += 4)
            rhs += cpt[(d + 0) * 128 + r] * wj[d + 0]
                 + cpt[(d + 1) * 128 + r] * wj[d + 1]
                 + cpt[(d + 2) * 128 + r] * wj[d + 2]
                 + cpt[(d + 3) * 128 + r] * wj[d + 3];
    }
    float x = 0.f, res = rhs, p = rhs;
    if (lo) p_s[r] = p;
    float rr = blk_red256(lo ? res * res : 0.f, rbuf, t);
    __syncthreads();   // G + p_s visible
    if (j == 0) {      // L2new folded here
        float s = 0.f;
        if (lo) {
            #pragma unroll 8
            for (int c = 0; c < 128; ++c) s += G[r * GSTR + c];
            s -= G[r * GSTR + r];
        }
        float tot = blk_red256(s, rbuf + 8, t);
        if (t == 0) out_l2new[0] = tot / 16384.0f;
    }
    for (int it = 0; it < 20; ++it) {
        float q = 0.f;
        if (lo) {
            #pragma unroll 8
            for (int c = 0; c < 128; c += 4) {
                float4 g  = *(const float4*)&G[r * GSTR + c];
                float4 pp = *(const float4*)&p_s[c];
                q += g.x * pp.x + g.y * pp.y + g.z * pp.z + g.w * pp.w;
            }
        }
        float pq = blk_red256(lo ? p * q : 0.f, rbuf + 4, t);
        float alpha = rr / pq;
        x += alpha * p;
        res -= alpha * q;
        float rrn = blk_red256(lo ? res * res : 0.f, rbuf, t);
        float beta = rrn / rr;
        rr = rrn;
        p = res + beta * p;
        if (lo) p_s[r] = p;
        __syncthreads();
    }
    if (lo) tsol[r * NCLS + j] = x;
    // ---- ct tail: ct[d][j] = cpt[d][:] . x ----
    if (lo) p_s[r] = x;
    __syncthreads();
    for (int d = t; d < D_DIM; d += 256) {
        const float* crow = cpt + d * 128;
        float s = 0.f;
        #pragma unroll 8
        for (int c = 0; c < 128; c += 4) {
            float4 cc = *(const float4*)(crow + c);
            float4 xx = *(const float4*)&p_s[c];
            s += cc.x * xx.x + cc.y * xx.y + cc.z * xx.z + cc.w * xx.w;
        }
        ct[d * NCLS + j] = s;
    }
}

__device__ __forceinline__ void old_role(char* smem, const float* __restrict__ pscore,
        const float* __restrict__ gram, float* __restrict__ out01) {
    float* ss2     = (float*)smem;             // 256
    float* sm2     = (float*)(smem + 1024);    // 256
    float* rcn_s   = (float*)(smem + 2048);    // 128
    float* wcomb   = (float*)(smem + 2560);    // 128
    float* redA    = (float*)(smem + 3072);    // 128
    float* redB    = (float*)(smem + 3584);    // 128
    float* wred4   = (float*)(smem + 4096);    // 4
    float* trace_s = (float*)(smem + 4112);    // 1
    const float* p0 = pscore;
    const float* p1 = pscore + NCLUST * 128;
    int t = threadIdx.x;
    int c = t & 127, w2 = t >> 7;
    if (t < 128) rcn_s[t] = 1.0f / fmaxf(sqrtf(gram[t * 129]), 1e-12f);
    __syncthreads();
    float rc = rcn_s[c];
    float ss = 0.f, sm = 0.f;
    for (int bb = 0; bb < 25; ++bb) {
        float a[10];
        #pragma unroll
        for (int k = 0; k < 10; ++k) {
            int cl = w2 + 2 * (10 * bb + k);
            a[k] = p0[cl * 128 + c] + p1[cl * 128 + c];
        }
        #pragma unroll
        for (int k = 0; k < 10; ++k) { float v = fabsf(a[k]) * rc; ss += v * v; sm += v; }
    }
    ss2[w2 * 128 + c] = ss; sm2[w2 * 128 + c] = sm;
    __syncthreads();
    if (t < 128) {
        float S = ss2[t] + ss2[128 + t];
        float M = sm2[t] + sm2[128 + t];
        float nn = fmaxf(sqrtf(S), 1e-12f);
        float iv = 1.0f / nn;
        wcomb[t] = rcn_s[t] * iv;
        redA[t] = M * iv;
        redB[t] = S * iv * iv;
    }
    __syncthreads();
    if (t < 64) {
        float a = redA[t] + redA[t + 64];
        float b2 = redB[t] + redB[t + 64];
        #pragma unroll
        for (int m = 32; m > 0; m >>= 1) { a += __shfl_xor(a, m); b2 += __shfl_xor(b2, m); }
        if (t == 0) { out01[0] = a; trace_s[0] = b2; }
    }
    __syncthreads();
    int w = t >> 6, lane = t & 63;
    float wc0 = wcomb[lane], wc1 = wcomb[lane + 64];
    float rsq = 0.f;
    for (int bb = 0; bb < 25; ++bb) {
        float a0[5], a1[5];
        #pragma unroll
        for (int k = 0; k < 5; ++k) {
            int cl = w + 4 * (5 * bb + k);
            a0[k] = p0[cl * 128 + lane] + p1[cl * 128 + lane];
            a1[k] = p0[cl * 128 + 64 + lane] + p1[cl * 128 + 64 + lane];
        }
        #pragma unroll
        for (int k = 0; k < 5; ++k) {
            float v = fabsf(a0[k]) * wc0 + fabsf(a1[k]) * wc1;
            #pragma unroll
            for (int m = 32; m > 0; m >>= 1) v += __shfl_xor(v, m);
            if (lane == 0) rsq += v * v;
        }
    }
    if (lane == 0) wred4[w] = rsq;
    __syncthreads();
    if (t == 0) out01[1] = wred4[0] + wred4[1] + wred4[2] + wred4[3] - trace_s[0];
}

__device__ __forceinline__ void P_role(char* smem, const float* __restrict__ E,
        const unsigned short* __restrict__ bimg, unsigned short* __restrict__ keyT,
        int blk) {
    char* lds = smem;                           // A dbuf 0..32K, B dbuf 32K..64K
    float* esq_s = (float*)(smem + 65536);      // 128
    unsigned short* cst = (unsigned short*)lds; // epilogue overlay [128][136]

    int t = threadIdx.x;
    int rowbase = blk * 128;
    int lane = t & 63, w = t >> 6;
    int wr = w >> 1, wc = w & 1;
    f32x4 acc[4][4];
    #pragma unroll
    for (int m = 0; m < 4; ++m)
        #pragma unroll
        for (int n = 0; n < 4; ++n) acc[m][n] = (f32x4){0.f, 0.f, 0.f, 0.f};
    float esq_p[4] = {0.f, 0.f, 0.f, 0.f};
    int g = t >> 3, k8 = t & 7;

    float4 a0[4], a1[4];
    bhalf8 breg[4];

    auto stage_issue = [&](int ks) {
        #pragma unroll
        for (int p = 0; p < 4; ++p) {
            int grow = rowbase + 32 * p + g;
            if (grow < M_TRAIN) {
                const float* src = E + (long)grow * D_DIM + ks * 64 + k8 * 8;
                a0[p] = *(const float4*)(src);
                a1[p] = *(const float4*)(src + 4);
            } else {
                a0[p] = make_float4(0.f, 0.f, 0.f, 0.f);
                a1[p] = make_float4(0.f, 0.f, 0.f, 0.f);
            }
        }
        const char* bs = (const char*)bimg + ks * 16384;
        #pragma unroll
        for (int i = 0; i < 4; ++i)
            breg[i] = *(const bhalf8*)(bs + (i * 256 + t) * 16);
    };
    auto stage_write = [&](int buf) {
        char* Ab = lds + buf * 16384;
        char* Bb = lds + 32768 + buf * 16384;
        #pragma unroll
        for (int p = 0; p < 4; ++p) {
            int row = 32 * p + g;
            float4 v0 = a0[p], v1 = a1[p];
            esq_p[p] += v0.x*v0.x + v0.y*v0.y + v0.z*v0.z + v0.w*v0.w
                      + v1.x*v1.x + v1.y*v1.y + v1.z*v1.z + v1.w*v1.w;
            union { bhalf8 v; unsigned int u[4]; } h;
            h.u[0] = f2bf2(v0.x, v0.y);
            h.u[1] = f2bf2(v0.z, v0.w);
            h.u[2] = f2bf2(v1.x, v1.y);
            h.u[3] = f2bf2(v1.z, v1.w);
            int byte = (row * 128 + k8 * 16) ^ ((row & 7) << 4);
            *(bhalf8*)(Ab + byte) = h.v;
        }
        #pragma unroll
        for (int i = 0; i < 4; ++i)
            *(bhalf8*)(Bb + (i * 256 + t) * 16) = breg[i];
    };

    stage_issue(0);
    stage_write(0);
    __syncthreads();
    int cur = 0;
    for (int ks = 0; ks < 12; ++ks) {
        if (ks < 11) stage_issue(ks + 1);
        const char* Ab = lds + cur * 16384;
        const char* Bb = lds + 32768 + cur * 16384;
        bhalf8 af[4][2], bf[4][2];
        int kb = (lane >> 4) * 16;
        #pragma unroll
        for (int m = 0; m < 4; ++m) {
            int row = wr * 64 + m * 16 + (lane & 15);
            int b0 = row * 128, sw = (row & 7) << 4;
            af[m][0] = *(const bhalf8*)(Ab + ((b0 + kb) ^ sw));
            af[m][1] = *(const bhalf8*)(Ab + ((b0 + kb + 64) ^ sw));
        }
        #pragma unroll
        for (int n = 0; n < 4; ++n) {
            int c = wc * 64 + n * 16 + (lane & 15);
            int b0 = c * 128, sw = (c & 7) << 4;
            bf[n][0] = *(const bhalf8*)(Bb + ((b0 + kb) ^ sw));
            bf[n][1] = *(const bhalf8*)(Bb + ((b0 + kb + 64) ^ sw));
        }
        #pragma unroll
        for (int m = 0; m < 4; ++m)
            #pragma unroll
            for (int n = 0; n < 4; ++n) {
                acc[m][n] = __builtin_amdgcn_mfma_f32_16x16x32_bf16(af[m][0], bf[n][0], acc[m][n], 0, 0, 0);
                acc[m][n] = __builtin_amdgcn_mfma_f32_16x16x32_bf16(af[m][1], bf[n][1], acc[m][n], 0, 0, 0);
            }
        if (ks < 11) stage_write(cur ^ 1);
        __syncthreads();
        cur ^= 1;
    }
    #pragma unroll
    for (int p = 0; p < 4; ++p) {
        float v = esq_p[p];
        v += __shfl_xor(v, 1); v += __shfl_xor(v, 2); v += __shfl_xor(v, 4);
        if (k8 == 0) esq_s[32 * p + g] = v;
    }
    __syncthreads();
    #pragma unroll
    for (int m = 0; m < 4; ++m) {
        int r0 = wr * 64 + m * 16 + (lane >> 4) * 4;
        float e0 = esq_s[r0], e1 = esq_s[r0 + 1], e2 = esq_s[r0 + 2], e3 = esq_s[r0 + 3];
        #pragma unroll
        for (int n = 0; n < 4; ++n) {
            int c = wc * 64 + n * 16 + (lane & 15);
            union { ushort4v v; unsigned int u[2]; } kv;
            kv.u[0] = f2bf2(e0 - 2.f * acc[m][n][0], e1 - 2.f * acc[m][n][1]);
            kv.u[1] = f2bf2(e2 - 2.f * acc[m][n][2], e3 - 2.f * acc[m][n][3]);
            *(ushort4v*)(cst + c * 136 + r0) = kv.v;
        }
    }
    __syncthreads();
    #pragma unroll
    for (int it = 0; it < 8; ++it) {
        int c = w * 32 + it * 4 + (lane >> 4);
        int r = (lane & 15) * 8;
        if (rowbase + r < M_TRAIN) {
            ushort8 v = *(const ushort8*)(cst + c * 136 + r);
            *(ushort8*)(keyT + (long)c * M_TRAIN + rowbase + r) = v;
        }
    }
}

__global__ void __launch_bounds__(256, 2) kB(const float* __restrict__ E,
        const unsigned short* __restrict__ bimg, unsigned short* __restrict__ keyT,
        const float* __restrict__ gram, const float* __restrict__ cpt,
        const float* __restrict__ whx, float* __restrict__ tsol,
        float* __restrict__ ct, float* __restrict__ out_scal,
        const float* __restrict__ pscore) {
    __shared__ __align__(16) char smem[68160];
    int b = blockIdx.x;
    if (b < 10)       cg_role(smem, gram, cpt, whx, tsol, ct, out_scal + 3, b);
    else if (b == 10) old_role(smem, pscore, gram, out_scal);
    else              P_role(smem, E, bimg, keyT, b - 11);
}

// ======================= kC: select(512) | ypred(512) =======================
__global__ void __launch_bounds__(256) kC(const unsigned short* __restrict__ keyT,
        int* __restrict__ cand, const float* __restrict__ te,
        const float* __restrict__ ct, const float* __restrict__ bhx,
        float* __restrict__ out) {
    __shared__ __align__(16) char smem[30720];
    int b = blockIdx.x, t = threadIdx.x;
    if (b < 512) {     // ---- select: per-(concept, quarter) top-16 ----
        int* sk  = (int*)smem;            // 2048
        int* si  = (int*)(smem + 8192);   // 2048
        int* wk  = (int*)(smem + 16384);
        int* wi  = (int*)(smem + 16400);
        int* wsl = (int*)(smem + 16416);
        int c = b >> 2, h = b & 3;
        const unsigned short* col = keyT + (long)c * M_TRAIN + h * CHUNKN;
        int base = h * CHUNKN;
        int tk[8], ti[8];
        #pragma unroll
        for (int i = 0; i < 8; ++i) { tk[i] = 0x7fffffff; ti[i] = 0x7fffffff; }
        for (int i = t; i < CHUNKN / 8; i += 256) {
            ushort8 v = *(const ushort8*)(col + i * 8);
            int idx = base + i * 8;
            #pragma unroll
            for (int q = 0; q < 8; ++q) {
                int cv = (int)v[q]; int ci = idx + q;
                if (cv < tk[7] || (cv == tk[7] && ci < ti[7])) {
                    #pragma unroll
                    for (int jj = 0; jj < 8; ++jj) {
                        bool sw = (cv < tk[jj]) || (cv == tk[jj] && ci < ti[jj]);
                        int ok = tk[jj]; int oi = ti[jj];
                        if (sw) { tk[jj] = cv; ti[jj] = ci; cv = ok; ci = oi; }
                    }
                }
            }
        }
        #pragma unroll
        for (int i = 0; i < 8; ++i) { sk[t * 8 + i] = tk[i]; si[t * 8 + i] = ti[i]; }
        __syncthreads();
        int lane = t & 63, w = t >> 6;
        for (int sel = 0; sel < CAND_PER; ++sel) {
            int bk = 0x7fffffff, bi = 0x7fffffff, bs = -1;
            #pragma unroll
            for (int i = 0; i < 8; ++i) {
                int s = t * 8 + i;
                int v = sk[s];
                if (v < bk || (v == bk && si[s] < bi)) { bk = v; bi = si[s]; bs = s; }
            }
            #pragma unroll
            for (int m = 32; m > 0; m >>= 1) {
                int ok = __shfl_xor(bk, m); int oi = __shfl_xor(bi, m); int os = __shfl_xor(bs, m);
                if (ok < bk || (ok == bk && oi < bi)) { bk = ok; bi = oi; bs = os; }
            }
            if (lane == 0) { wk[w] = bk; wi[w] = bi; wsl[w] = bs; }
            __syncthreads();
            if (t == 0) {
                int fk = wk[0], fi = wi[0], fs = wsl[0];
                for (int i = 1; i < 4; ++i)
                    if (wk[i] < fk || (wk[i] == fk && wi[i] < fi)) { fk = wk[i]; fi = wi[i]; fs = wsl[i]; }
                cand[(c * NCHUNK + h) * CAND_PER + sel] = fi;
                sk[fs] = 0x7fffffff; si[fs] = 0x7fffffff;
            }
            __syncthreads();
        }
    } else {           // ---- ypred ----
        float* ctT = (float*)smem;   // [NCLS][D_DIM]
        for (int o = t; o < D_DIM * NCLS; o += 256) {
            int j = o / D_DIM, d = o % D_DIM;
            ctT[j * D_DIM + d] = ct[d * NCLS + j];
        }
        __syncthreads();
        int r = t >> 5, l = t & 31;
        long row = (long)(b - 512) * 8 + r;
        const float* er = te + row * D_DIM;
        float acc[NCLS];
        #pragma unroll
        for (int j = 0; j < NCLS; ++j) acc[j] = 0.f;
        for (int d0 = l * 4; d0 < D_DIM; d0 += 128) {
            float4 e = *(const float4*)(er + d0);
            #pragma unroll
            for (int j = 0; j < NCLS; ++j) {
                float4 cc = *(const float4*)(&ctT[j * D_DIM + d0]);
                acc[j] += e.x*cc.x + e.y*cc.y + e.z*cc.z + e.w*cc.w;
            }
        }
        #pragma unroll
        for (int j = 0; j < NCLS; ++j) {
            #pragma unroll
            for (int m = 16; m > 0; m >>= 1) acc[j] += __shfl_xor(acc[j], m);
        }
        if (l == 0) {
            #pragma unroll
            for (int j = 0; j < NCLS; ++j) out[row * NCLS + j] = acc[j] + bhx[j];
        }
    }
}

// ======================= kD: refine(128) =======================
__global__ void __launch_bounds__(256) kD(const float* __restrict__ E,
        const float* __restrict__ conceptT, const int* __restrict__ cand,
        float* __restrict__ psum) {
    __shared__ float skey[NCT], sdot[NCT];
    __shared__ int sidx[NCT];
    int c = blockIdx.x, t = threadIdx.x;
    int g = t >> 2, l4 = t & 3;
    int idx = cand[c * NCT + g];
    const float* er = E + (long)idx * D_DIM;
    const float* cr = conceptT + c * D_DIM;
    float dot = 0.f, ss = 0.f;
    for (int d0 = l4 * 4; d0 < D_DIM; d0 += 16) {
        float4 e = *(const float4*)(er + d0);
        float4 cc = *(const float4*)(cr + d0);
        dot += e.x*cc.x + e.y*cc.y + e.z*cc.z + e.w*cc.w;
        ss  += e.x*e.x + e.y*e.y + e.z*e.z + e.w*e.w;
    }
    dot += __shfl_xor(dot, 1); dot += __shfl_xor(dot, 2);
    ss  += __shfl_xor(ss, 1);  ss  += __shfl_xor(ss, 2);
    if (l4 == 0) { skey[g] = ss - 2.f * dot; sdot[g] = dot; sidx[g] = idx; }
    __syncthreads();
    if (t == 0) {
        float sum = 0.f;
        unsigned long long used = 0ull;
        for (int s = 0; s < KSEL; ++s) {
            float bk = FLT_INF; int bi = 0x7fffffff, bs = 0;
            for (int i = 0; i < NCT; ++i) {
                if ((used >> i) & 1ull) continue;
                if (skey[i] < bk || (skey[i] == bk && sidx[i] < bi)) { bk = skey[i]; bi = sidx[i]; bs = i; }
            }
            used |= (1ull << bs);
            sum += sdot[bs];
        }
        psum[c] = sum;
    }
}

__global__ void k_finalize(const float* __restrict__ psum, float* __restrict__ out2) {
    __shared__ float red[128];
    int t = threadIdx.x;
    red[t] = psum[t];
    __syncthreads();
    for (int s = 64; s > 0; s >>= 1) { if (t < s) red[t] += red[t + s]; __syncthreads(); }
    if (t == 0) out2[0] = red[0] * (1.0f / (C_DIM * KSEL));
}

extern "C" void kernel_launch(void* const* d_in, const int* in_sizes, int n_in,
                              void* d_out, int out_size, void* d_ws, size_t ws_size,
                              hipStream_t stream) {
    (void)in_sizes; (void)n_in; (void)out_size; (void)ws_size;
    const float* te   = (const float*)d_in[0];  // 4096x768
    const float* cpt  = (const float*)d_in[1];  // 768x128
    const float* clus = (const float*)d_in[2];  // 500x100x768
    const float* tes  = (const float*)d_in[3];  // 100000x768
    const float* whx  = (const float*)d_in[4];  // 10x768
    const float* bhx  = (const float*)d_in[5];  // 10
    float* out = (float*)d_out;                 // 40960 y_pred + 4 scalars
    char* ws = (char*)d_ws;
    unsigned short* keyT  = (unsigned short*)(ws + WS_KEYT);
    unsigned short* bimg  = (unsigned short*)(ws + WS_BIMG);
    float* conceptT       = (float*)(ws + WS_CONT);
    float* gram           = (float*)(ws + WS_GRAM);
    float* pscore         = (float*)(ws + WS_PSCORE);
    float* ct             = (float*)(ws + WS_CT);
    int* cand             = (int*)(ws + WS_CAND);
    float* psum           = (float*)(ws + WS_PSUM);
    float* tsol           = (float*)(ws + WS_TSOL);

    kA<<<dim3(1448), dim3(256), 0, stream>>>(cpt, clus, conceptT, bimg, gram, pscore);
    kB<<<dim3(793),  dim3(256), 0, stream>>>(tes, bimg, keyT, gram, cpt, whx, tsol, ct,
                                             out + 40960, pscore);
    kC<<<dim3(1024), dim3(256), 0, stream>>>(keyT, cand, te, ct, bhx, out);
    kD<<<dim3(128),  dim3(256), 0, stream>>>(tes, conceptT, cand, psum);
    k_finalize<<<dim3(1), dim3(128), 0, stream>>>(psum, out + 40962);
}